// Round 1
// baseline (507.871 us; speedup 1.0000x reference)
//
#include <hip/hip_runtime.h>

// Fused SFAM, merged-direction kernel: one WG per (b,h) row-pair computes BOTH
// out_l and out_r. Exact two-pass softmax over the shared 320x320 score matrix
// (row stats for r->l, col stats for l->r). Key-side Q projection eliminated:
// S = (Q_l W~_r) x^_r^T + (Q_l b~_r) 1^T, so K = raw-LN x^_r.
// v2: 1024 threads = 16 waves (4 waves/SIMD vs 2) to attack the latency bound:
//  - 20 row-tiles over 16 waves -> per-wave critical path 3 -> 2 tiles
//  - staging/stats fused per-(side,w) with b128 LDS writes (SR buffer removed)
//  - colmax via ds_max_u32 atomics with monotone float->uint keys
//  - epilogue reads rows via b128
// LDS 160,768 B -> still 1 WG/CU (core buffers Rs+Ks+Vb=134KB are irreducible
// without a streaming redesign), but intra-WG wave parallelism doubles.

#define HWs  57600      // H*W
#define CHWs 3686400    // C*H*W
#define TOTs 14745600   // B*C*H*W
#define RST  72         // pixel-major row stride (ushort): 64 + 8 pad
#define VST  328        // channel-major row stride (ushort): 320 + 8 pad
#define PTS  36         // Pt row stride (ushort): 32 + 4 pad

typedef short bf16x8 __attribute__((ext_vector_type(8)));
typedef float f32x4  __attribute__((ext_vector_type(4)));
union FragU { uint4 q; unsigned short u[8]; bf16x8 v; };

__device__ __forceinline__ unsigned short f2bf(float f) {
  unsigned u = __float_as_uint(f);
  u += 0x7fffu + ((u >> 16) & 1u);     // RNE
  return (unsigned short)(u >> 16);
}
__device__ __forceinline__ float bf2f(unsigned short s) {
  return __uint_as_float(((unsigned)s) << 16);
}
// monotone float<->uint keys so colmax can use native ds_max_u32
__device__ __forceinline__ unsigned fenc(float f) {
  unsigned u = __float_as_uint(f);
  return u ^ (0x80000000u | (unsigned)(-(int)(u >> 31)));
}
__device__ __forceinline__ float fdec(unsigned k) {
  return __uint_as_float(k ^ (0x80000000u | (unsigned)(-(int)((k >> 31) ^ 1u))));
}

__global__ __launch_bounds__(1024) void sfam_kernel(
    const float* __restrict__ x_l, const float* __restrict__ x_r,
    const float* __restrict__ ln_l_w, const float* __restrict__ ln_l_b,
    const float* __restrict__ ln_r_w, const float* __restrict__ ln_r_b,
    const float* __restrict__ wq_l, const float* __restrict__ bq_l,
    const float* __restrict__ wq_r, const float* __restrict__ bq_r,
    const float* __restrict__ wv_l, const float* __restrict__ bv_l,
    const float* __restrict__ wv_r, const float* __restrict__ bv_r,
    const float* __restrict__ beta, const float* __restrict__ gamma,
    float* __restrict__ out)
{
  // LDS: 46080 + 46080 + 41984 + 18432 + 1280 + 2560 + 2560 + 1280 + 512
  //    = 160768 B  (<= 163840)
  __shared__ __align__(16) unsigned short Rs[320*RST]; // x_l raw -> Q_l -> Q_l'' -> O_r
  __shared__ __align__(16) unsigned short Ks[320*RST]; // x_r raw -> x^_r -> O_l
  __shared__ __align__(16) unsigned short Vb[64*VST];  // V_l then V_r (channel-major)
  __shared__ __align__(16) unsigned short Pt[16*16*PTS];// per-wave P->A round-trip
  __shared__ unsigned CMu[320]; // colmax as monotone uint keys (ds_max_u32)
  __shared__ float MU[640], RSd[640];  // LN stats, [0..320)=l, [320..640)=r
  __shared__ float c_arr[320];  // c_wl = 0.125 * Q_l . b~_r
  __shared__ float BB[128];     // [0..64)=b~_l, [64..128)=b~_r

  const int bh = blockIdx.x;
  const int b = bh / 180, h = bh - b*180;
  const int base = b*CHWs + h*320;

  const int t = threadIdx.x;
  const int wave = t >> 6, lane = t & 63;
  const int p = lane & 15, g = lane >> 4;
  // 20 row-tiles over 16 waves: waves 0-3 take 2, waves 4-15 take 1
  const int nwt = (wave < 4) ? 2 : 1;
  const int w0 = (wave < 4) ? wave*32 : 128 + (wave-4)*16;

  // ---------- A: staging + inline LN stats (one thread per (side,w)) ----------
  for (int w2 = t; w2 < 640; w2 += 1024) {
    const int side = (w2 >= 320);
    const int w = w2 - side*320;
    const float* xp = side ? x_r : x_l;
    unsigned short* dst = side ? Ks : Rs;
    // two sequential half-sums to match previous summation order bit-exactly
    float s0 = 0.f, q0 = 0.f, s1 = 0.f, q1 = 0.f;
    #pragma unroll
    for (int cb = 0; cb < 64; cb += 8) {
      FragU f;
      #pragma unroll
      for (int j = 0; j < 8; ++j) {
        const float v = xp[base + (cb+j)*HWs + w];
        if (cb < 32) { s0 += v; q0 += v*v; } else { s1 += v; q1 += v*v; }
        f.u[j] = f2bf(v);
      }
      *(uint4*)&dst[w*RST + cb] = f.q;
    }
    const float m  = (s0 + s1) * (1.f/64.f);
    const float vv = (q0 + q1) * (1.f/64.f) - m*m;
    MU[side*320 + w]  = m;
    RSd[side*320 + w] = rsqrtf(vv + 1e-6f);
  }
  if (t < 320) CMu[t] = 0u;   // key 0 == very negative float
  if (t < 128) {   // effective Q biases: b~ = bq + (W .* lnw) @ lnb
    const int o = t & 63;
    const float* wqp = (t < 64) ? wq_l : wq_r;
    const float* lwp = (t < 64) ? ln_l_w : ln_r_w;
    const float* lbp = (t < 64) ? ln_l_b : ln_r_b;
    const float* bqp = (t < 64) ? bq_l : bq_r;
    float s = bqp[o];
    for (int c = 0; c < 64; ++c) s += wqp[o*64+c]*lwp[c]*lbp[c];
    BB[t] = s;
  }
  __syncthreads();

  // ---------- V projection (A = Wv, B = raw x rows; all row-local) ----------
  auto projV = [&](const float* wvp, const float* bvp, const unsigned short* src,
                   const float* mup, const float* rsp, bool inv) {
    bf16x8 bx[2][2];
    #pragma unroll
    for (int nt = 0; nt < 2; ++nt) if (nt < nwt) {
      const int w = w0 + nt*16 + p;
      const float mu = mup[w];
      const float sd = inv ? (1.0f / rsp[w]) : 0.f;
      #pragma unroll
      for (int kf = 0; kf < 2; ++kf) {
        FragU f; f.q = *(const uint4*)&src[w*RST + kf*32 + g*8];
        if (inv) {           // recover raw x from normalized: x = x^*sd + mu
          FragU rr;
          #pragma unroll
          for (int j = 0; j < 8; ++j) rr.u[j] = f2bf(bf2f(f.u[j])*sd + mu);
          bx[nt][kf] = rr.v;
        } else bx[nt][kf] = f.v;
      }
    }
    bf16x8 av[4][2];
    #pragma unroll
    for (int mt = 0; mt < 4; ++mt)
      #pragma unroll
      for (int kf = 0; kf < 2; ++kf) {
        FragU rr;
        #pragma unroll
        for (int j = 0; j < 8; ++j) rr.u[j] = f2bf(wvp[(mt*16+p)*64 + kf*32 + g*8 + j]);
        av[mt][kf] = rr.v;
      }
    f32x4 acc[4][2];
    #pragma unroll
    for (int mt = 0; mt < 4; ++mt)
      #pragma unroll
      for (int nt = 0; nt < 2; ++nt) acc[mt][nt] = (f32x4){0.f,0.f,0.f,0.f};
    #pragma unroll
    for (int mt = 0; mt < 4; ++mt)
      #pragma unroll
      for (int nt = 0; nt < 2; ++nt) if (nt < nwt)
        #pragma unroll
        for (int kf = 0; kf < 2; ++kf)
          acc[mt][nt] = __builtin_amdgcn_mfma_f32_16x16x32_bf16(av[mt][kf], bx[nt][kf], acc[mt][nt], 0,0,0);
    #pragma unroll
    for (int mt = 0; mt < 4; ++mt)
      #pragma unroll
      for (int nt = 0; nt < 2; ++nt) if (nt < nwt)
        #pragma unroll
        for (int r = 0; r < 4; ++r) {
          const int o = mt*16 + g*4 + r;
          Vb[o*VST + w0 + nt*16 + p] = f2bf(acc[mt][nt][r] + bvp[o]);
        }
  };

  projV(wv_l, bv_l, Rs, MU, RSd, false);   // Vb = V_l (from raw x_l)

  // ---------- Q_l = LN(x_l) W~_l^T + b~_l  (write in place to Rs) ----------
  float cR[2][4];
  {
    bf16x8 qa[2][2];
    #pragma unroll
    for (int wt = 0; wt < 2; ++wt) if (wt < nwt) {
      const int w = w0 + wt*16 + p;
      const float mu = MU[w], rs = RSd[w];
      #pragma unroll
      for (int kf = 0; kf < 2; ++kf) {
        FragU f; f.q = *(const uint4*)&Rs[w*RST + kf*32 + g*8];
        FragU rr;
        #pragma unroll
        for (int j = 0; j < 8; ++j) rr.u[j] = f2bf((bf2f(f.u[j]) - mu) * rs);
        qa[wt][kf] = rr.v;
      }
    }
    bf16x8 bw[4][2];
    #pragma unroll
    for (int ot = 0; ot < 4; ++ot)
      #pragma unroll
      for (int kf = 0; kf < 2; ++kf) {
        FragU rr;
        #pragma unroll
        for (int j = 0; j < 8; ++j) {
          const int c = kf*32 + g*8 + j;
          rr.u[j] = f2bf(wq_l[(ot*16+p)*64 + c] * ln_l_w[c]);
        }
        bw[ot][kf] = rr.v;
      }
    f32x4 qacc[2][4];
    #pragma unroll
    for (int wt = 0; wt < 2; ++wt)
      #pragma unroll
      for (int ot = 0; ot < 4; ++ot) qacc[wt][ot] = (f32x4){0.f,0.f,0.f,0.f};
    #pragma unroll
    for (int wt = 0; wt < 2; ++wt) if (wt < nwt)
      #pragma unroll
      for (int ot = 0; ot < 4; ++ot)
        #pragma unroll
        for (int kf = 0; kf < 2; ++kf)
          qacc[wt][ot] = __builtin_amdgcn_mfma_f32_16x16x32_bf16(qa[wt][kf], bw[ot][kf], qacc[wt][ot], 0,0,0);
    // += b~_l, write Q_l, accumulate c = Q_l . b~_r
    #pragma unroll
    for (int wt = 0; wt < 2; ++wt) {
      #pragma unroll
      for (int r = 0; r < 4; ++r) cR[wt][r] = 0.f;
      if (wt < nwt) {
        #pragma unroll
        for (int ot = 0; ot < 4; ++ot) {
          const float bl = BB[ot*16+p], br = BB[64 + ot*16+p];
          #pragma unroll
          for (int r = 0; r < 4; ++r) {
            const float qv = qacc[wt][ot][r] + bl;
            Rs[(w0 + wt*16 + g*4 + r)*RST + ot*16 + p] = f2bf(qv);
            cR[wt][r] += qv * br;
          }
        }
        #pragma unroll
        for (int r = 0; r < 4; ++r) {
          float cv = cR[wt][r];
          cv += __shfl_xor(cv, 1); cv += __shfl_xor(cv, 2);
          cv += __shfl_xor(cv, 4); cv += __shfl_xor(cv, 8);
          cv *= 0.125f;
          cR[wt][r] = cv;
          if (p == 0) c_arr[w0 + wt*16 + g*4 + r] = cv;
        }
      }
    }
  }

  // ---------- Q_l'' = 0.125 * Q_l W~_r  (in place to Rs) ----------
  {
    bf16x8 qla[2][2];
    #pragma unroll
    for (int wt = 0; wt < 2; ++wt) if (wt < nwt)
      #pragma unroll
      for (int kf = 0; kf < 2; ++kf) {
        FragU f; f.q = *(const uint4*)&Rs[(w0 + wt*16 + p)*RST + kf*32 + g*8];
        qla[wt][kf] = f.v;
      }
    bf16x8 bwt[4][2];
    #pragma unroll
    for (int ct = 0; ct < 4; ++ct) {
      const float lw = ln_r_w[ct*16 + p];
      #pragma unroll
      for (int kf = 0; kf < 2; ++kf) {
        FragU rr;
        #pragma unroll
        for (int j = 0; j < 8; ++j)
          rr.u[j] = f2bf(wq_r[(kf*32 + g*8 + j)*64 + ct*16 + p] * lw);
        bwt[ct][kf] = rr.v;
      }
    }
    f32x4 q2[2][4];
    #pragma unroll
    for (int wt = 0; wt < 2; ++wt)
      #pragma unroll
      for (int ct = 0; ct < 4; ++ct) q2[wt][ct] = (f32x4){0.f,0.f,0.f,0.f};
    #pragma unroll
    for (int wt = 0; wt < 2; ++wt) if (wt < nwt)
      #pragma unroll
      for (int ct = 0; ct < 4; ++ct)
        #pragma unroll
        for (int kf = 0; kf < 2; ++kf)
          q2[wt][ct] = __builtin_amdgcn_mfma_f32_16x16x32_bf16(qla[wt][kf], bwt[ct][kf], q2[wt][ct], 0,0,0);
    #pragma unroll
    for (int wt = 0; wt < 2; ++wt) if (wt < nwt)
      #pragma unroll
      for (int ct = 0; ct < 4; ++ct)
        #pragma unroll
        for (int r = 0; r < 4; ++r)
          Rs[(w0 + wt*16 + g*4 + r)*RST + ct*16 + p] = f2bf(q2[wt][ct][r] * 0.125f);
  }

  // ---------- normalize Ks in place: x^_r = (x_r - mu) * rs ----------
  #pragma unroll
  for (int wt = 0; wt < 2; ++wt) if (wt < nwt) {
    const int w = w0 + wt*16 + p;
    const float mu = MU[320+w], rs = RSd[320+w];
    #pragma unroll
    for (int kf = 0; kf < 2; ++kf) {
      FragU f; f.q = *(const uint4*)&Ks[w*RST + kf*32 + g*8];
      FragU rr;
      #pragma unroll
      for (int j = 0; j < 8; ++j) rr.u[j] = f2bf((bf2f(f.u[j]) - mu) * rs);
      *(uint4*)&Ks[w*RST + kf*32 + g*8] = rr.q;
    }
  }
  __syncthreads();   // Rs=Q_l'', Ks=x^_r, Vb=V_l, c_arr all visible

  // ---------- persistent A-frags ----------
  bf16x8 aq[2][2], ak[2][2];
  #pragma unroll
  for (int wt = 0; wt < 2; ++wt) if (wt < nwt)
    #pragma unroll
    for (int kf = 0; kf < 2; ++kf) {
      FragU f1; f1.q = *(const uint4*)&Rs[(w0 + wt*16 + p)*RST + kf*32 + g*8];
      aq[wt][kf] = f1.v;
      FragU f2; f2.q = *(const uint4*)&Ks[(w0 + wt*16 + p)*RST + kf*32 + g*8];
      ak[wt][kf] = f2.v;
    }

  // ---------- pass 1: S stats (rowmax exact per wave; colmax via ds_max_u32) ----------
  float rm[2][4];
  #pragma unroll
  for (int wt = 0; wt < 2; ++wt)
    #pragma unroll
    for (int r = 0; r < 4; ++r) rm[wt][r] = -3.0e38f;
  for (int ch = 0; ch < 5; ++ch) {
    const int k0 = ch*64;
    bf16x8 bq[4][2];
    #pragma unroll
    for (int vt = 0; vt < 4; ++vt)
      #pragma unroll
      for (int kf = 0; kf < 2; ++kf) {
        FragU f; f.q = *(const uint4*)&Ks[(k0 + vt*16 + p)*RST + kf*32 + g*8];
        bq[vt][kf] = f.v;
      }
    f32x4 sacc[2][4];
    #pragma unroll
    for (int wt = 0; wt < 2; ++wt)
      #pragma unroll
      for (int vt = 0; vt < 4; ++vt) sacc[wt][vt] = (f32x4){0.f,0.f,0.f,0.f};
    #pragma unroll
    for (int wt = 0; wt < 2; ++wt) if (wt < nwt)
      #pragma unroll
      for (int vt = 0; vt < 4; ++vt)
        #pragma unroll
        for (int kf = 0; kf < 2; ++kf)
          sacc[wt][vt] = __builtin_amdgcn_mfma_f32_16x16x32_bf16(aq[wt][kf], bq[vt][kf], sacc[wt][vt], 0,0,0);
    #pragma unroll
    for (int wt = 0; wt < 2; ++wt) if (wt < nwt) {
      #pragma unroll
      for (int r = 0; r < 4; ++r) {
        float m4 = fmaxf(fmaxf(sacc[wt][0][r], sacc[wt][1][r]),
                         fmaxf(sacc[wt][2][r], sacc[wt][3][r])) + cR[wt][r];
        m4 = fmaxf(m4, __shfl_xor(m4, 1)); m4 = fmaxf(m4, __shfl_xor(m4, 2));
        m4 = fmaxf(m4, __shfl_xor(m4, 4)); m4 = fmaxf(m4, __shfl_xor(m4, 8));
        rm[wt][r] = fmaxf(rm[wt][r], m4);
      }
    }
    #pragma unroll
    for (int vt = 0; vt < 4; ++vt) {
      float cp = -3.0e38f;
      #pragma unroll
      for (int wt = 0; wt < 2; ++wt) if (wt < nwt)
        #pragma unroll
        for (int r = 0; r < 4; ++r) cp = fmaxf(cp, sacc[wt][vt][r] + cR[wt][r]);
      cp = fmaxf(cp, __shfl_xor(cp, 16));
      cp = fmaxf(cp, __shfl_xor(cp, 32));
      if (g == 0) atomicMax(&CMu[k0 + vt*16 + p], fenc(cp));
    }
  }
  __syncthreads();   // all colmax atomics done

  // ---------- shared attention pass (exp + row-sum + PV) ----------
  float ls[2][4];
  f32x4 oacc[2][4];
  auto attn_pass = [&](bf16x8 (&A)[2][2], const unsigned short* Bsrc,
                       float (&mx)[2][4], bool colc) {
    for (int ch = 0; ch < 5; ++ch) {
      const int k0 = ch*64;
      bf16x8 bq[4][2];
      #pragma unroll
      for (int vt = 0; vt < 4; ++vt)
        #pragma unroll
        for (int kf = 0; kf < 2; ++kf) {
          FragU f; f.q = *(const uint4*)&Bsrc[(k0 + vt*16 + p)*RST + kf*32 + g*8];
          bq[vt][kf] = f.v;
        }
      float cc4[4];
      #pragma unroll
      for (int vt = 0; vt < 4; ++vt) cc4[vt] = colc ? c_arr[k0 + vt*16 + p] : 0.f;
      f32x4 sacc[2][4];
      #pragma unroll
      for (int wt = 0; wt < 2; ++wt)
        #pragma unroll
        for (int vt = 0; vt < 4; ++vt) sacc[wt][vt] = (f32x4){0.f,0.f,0.f,0.f};
      #pragma unroll
      for (int wt = 0; wt < 2; ++wt) if (wt < nwt)
        #pragma unroll
        for (int vt = 0; vt < 4; ++vt)
          #pragma unroll
          for (int kf = 0; kf < 2; ++kf)
            sacc[wt][vt] = __builtin_amdgcn_mfma_f32_16x16x32_bf16(A[wt][kf], bq[vt][kf], sacc[wt][vt], 0,0,0);
      #pragma unroll
      for (int wt = 0; wt < 2; ++wt) if (wt < nwt) {
        #pragma unroll
        for (int r = 0; r < 4; ++r) {
          const float rc = colc ? 0.f : cR[wt][r];
          float rsum = 0.f;
          #pragma unroll
          for (int vt = 0; vt < 4; ++vt) {
            const float e = __expf(sacc[wt][vt][r] + rc + cc4[vt] - mx[wt][r]);
            sacc[wt][vt][r] = e; rsum += e;
          }
          rsum += __shfl_xor(rsum, 1); rsum += __shfl_xor(rsum, 2);
          rsum += __shfl_xor(rsum, 4); rsum += __shfl_xor(rsum, 8);
          ls[wt][r] += rsum;
        }
      }
      bf16x8 bvv[2][4];
      #pragma unroll
      for (int kf = 0; kf < 2; ++kf)
        #pragma unroll
        for (int ot = 0; ot < 4; ++ot) {
          FragU f; f.q = *(const uint4*)&Vb[(ot*16+p)*VST + k0 + kf*32 + g*8];
          bvv[kf][ot] = f.v;
        }
      unsigned short* ptw = &Pt[wave*16*PTS];
      #pragma unroll
      for (int wt = 0; wt < 2; ++wt) if (wt < nwt) {
        #pragma unroll
        for (int kf = 0; kf < 2; ++kf) {
          #pragma unroll
          for (int vh = 0; vh < 2; ++vh) {
            const int vt2 = kf*2 + vh;
            #pragma unroll
            for (int r = 0; r < 4; ++r)
              ptw[(g*4 + r)*PTS + vh*16 + p] = f2bf(sacc[wt][vt2][r]);
          }
          FragU fa; fa.q = *(const uint4*)&ptw[p*PTS + g*8];
          #pragma unroll
          for (int ot = 0; ot < 4; ++ot)
            oacc[wt][ot] = __builtin_amdgcn_mfma_f32_16x16x32_bf16(fa.v, bvv[kf][ot], oacc[wt][ot], 0,0,0);
        }
      }
    }
  };

  // ---------- pass 2b: dir1 (l->r). rows = wr, A = x^_r, B = Q_l'', V = V_l ----------
  float cmR[2][4];
  #pragma unroll
  for (int wt = 0; wt < 2; ++wt)
    #pragma unroll
    for (int r = 0; r < 4; ++r) {
      cmR[wt][r] = (wt < nwt) ? fdec(CMu[w0 + wt*16 + g*4 + r]) : 0.f;
      ls[wt][r] = 0.f;
    }
  #pragma unroll
  for (int wt = 0; wt < 2; ++wt)
    #pragma unroll
    for (int ot = 0; ot < 4; ++ot) oacc[wt][ot] = (f32x4){0.f,0.f,0.f,0.f};
  attn_pass(ak, Rs, cmR, true);
  __syncthreads();   // everyone done reading Rs (Q_l'') and Vb (V_l)

  // stash O_r -> Rs (normalized by colsum)
  #pragma unroll
  for (int wt = 0; wt < 2; ++wt) if (wt < nwt)
    #pragma unroll
    for (int r = 0; r < 4; ++r) {
      const float inv = 1.0f / ls[wt][r];
      #pragma unroll
      for (int ot = 0; ot < 4; ++ot)
        Rs[(w0 + wt*16 + g*4 + r)*RST + ot*16 + p] = f2bf(oacc[wt][ot][r] * inv);
    }

  // recompute V_r from normalized Ks (inverse LN), overwrite Vb
  projV(wv_r, bv_r, Ks, MU+320, RSd+320, true);
  __syncthreads();

  // ---------- pass 2a: dir0 (r->l). rows = wl, A = Q_l'', B = x^_r, V = V_r ----------
  #pragma unroll
  for (int wt = 0; wt < 2; ++wt)
    #pragma unroll
    for (int r = 0; r < 4; ++r) ls[wt][r] = 0.f;
  #pragma unroll
  for (int wt = 0; wt < 2; ++wt)
    #pragma unroll
    for (int ot = 0; ot < 4; ++ot) oacc[wt][ot] = (f32x4){0.f,0.f,0.f,0.f};
  attn_pass(aq, Ks, rm, false);
  __syncthreads();   // everyone done reading Ks (x^_r) and Vb (V_r)

  // stash O_l -> Ks (normalized by rowsum)
  #pragma unroll
  for (int wt = 0; wt < 2; ++wt) if (wt < nwt)
    #pragma unroll
    for (int r = 0; r < 4; ++r) {
      const float inv = 1.0f / ls[wt][r];
      #pragma unroll
      for (int ot = 0; ot < 4; ++ot)
        Ks[(w0 + wt*16 + g*4 + r)*RST + ot*16 + p] = f2bf(oacc[wt][ot][r] * inv);
    }
  __syncthreads();

  // ---------- epilogue: residual add + store, both sides (b128 row reads) ----------
  for (int w2 = t; w2 < 640; w2 += 1024) {
    const int side = (w2 >= 320);
    const int w = w2 - side*320;
    const float* xs = side ? x_r : x_l;
    const unsigned short* Osrc = side ? Rs : Ks;   // O_r in Rs, O_l in Ks
    const float* sc = side ? gamma : beta;
    float* op = out + (side ? TOTs : 0);
    #pragma unroll
    for (int cb = 0; cb < 64; cb += 8) {
      FragU f; f.q = *(const uint4*)&Osrc[w*RST + cb];
      #pragma unroll
      for (int j = 0; j < 8; ++j) {
        const int cc = cb + j;
        const int gi = base + cc*HWs + w;
        op[gi] = xs[gi] + sc[cc] * bf2f(f.u[j]);
      }
    }
  }
}

extern "C" void kernel_launch(void* const* d_in, const int* in_sizes, int n_in,
                              void* d_out, int out_size, void* d_ws, size_t ws_size,
                              hipStream_t stream) {
  (void)in_sizes; (void)n_in; (void)d_ws; (void)ws_size; (void)out_size;
  sfam_kernel<<<dim3(720), dim3(1024), 0, stream>>>(
      (const float*)d_in[0],  (const float*)d_in[1],
      (const float*)d_in[2],  (const float*)d_in[3],
      (const float*)d_in[4],  (const float*)d_in[5],
      (const float*)d_in[6],  (const float*)d_in[7],
      (const float*)d_in[8],  (const float*)d_in[9],
      (const float*)d_in[10], (const float*)d_in[11],
      (const float*)d_in[12], (const float*)d_in[13],
      (const float*)d_in[14], (const float*)d_in[15],
      (float*)d_out);
}

// Round 3
// 465.169 us; speedup vs baseline: 1.0918x; 1.0918x over previous
//
#include <hip/hip_runtime.h>

// Fused SFAM, merged-direction kernel: one WG per (b,h) row-pair computes BOTH
// out_l and out_r. Exact two-pass softmax over the shared 320x320 score matrix
// (row stats for r->l, col stats for l->r). Key-side Q projection eliminated:
// S = (Q_l W~_r) x^_r^T + (Q_l b~_r) 1^T, so K = raw-LN x^_r.
// v3b: 768 threads = 12 waves (3 waves/SIMD). v2's 16-wave version capped VGPRs
// at 64 -> ~300MB of scratch spill traffic (WRITE_SIZE 145->384MB). 12 waves
// keeps v2's 2-tile critical path (8 waves x 2 tiles + 4 waves x 1 tile) while
// raising the VGPR cap to ~168. Occupancy pinned via __launch_bounds__(768, 3)
// (2nd arg = min waves per EU on CDNA), the harness-proven spelling, instead of
// the amdgpu_waves_per_eu attribute (suspect in the round-2 container failure).
//  - staging/stats fused per-(side,w) with b128 LDS writes
//  - colmax via ds_max_u32 atomics with monotone float->uint keys
//  - epilogue reads rows via b128
// LDS 156,160 B -> 1 WG/CU.

#define HWs  57600      // H*W
#define CHWs 3686400    // C*H*W
#define TOTs 14745600   // B*C*H*W
#define RST  72         // pixel-major row stride (ushort): 64 + 8 pad
#define VST  328        // channel-major row stride (ushort): 320 + 8 pad
#define PTS  36         // Pt row stride (ushort): 32 + 4 pad
#define NTH  768        // 12 waves

typedef short bf16x8 __attribute__((ext_vector_type(8)));
typedef float f32x4  __attribute__((ext_vector_type(4)));
union FragU { uint4 q; unsigned short u[8]; bf16x8 v; };

__device__ __forceinline__ unsigned short f2bf(float f) {
  unsigned u = __float_as_uint(f);
  u += 0x7fffu + ((u >> 16) & 1u);     // RNE
  return (unsigned short)(u >> 16);
}
__device__ __forceinline__ float bf2f(unsigned short s) {
  return __uint_as_float(((unsigned)s) << 16);
}
// monotone float<->uint keys so colmax can use native ds_max_u32
__device__ __forceinline__ unsigned fenc(float f) {
  unsigned u = __float_as_uint(f);
  return u ^ (0x80000000u | (unsigned)(-(int)(u >> 31)));
}
__device__ __forceinline__ float fdec(unsigned k) {
  return __uint_as_float(k ^ (0x80000000u | (unsigned)(-(int)((k >> 31) ^ 1u))));
}

__global__ __launch_bounds__(NTH, 3)
void sfam_kernel(
    const float* __restrict__ x_l, const float* __restrict__ x_r,
    const float* __restrict__ ln_l_w, const float* __restrict__ ln_l_b,
    const float* __restrict__ ln_r_w, const float* __restrict__ ln_r_b,
    const float* __restrict__ wq_l, const float* __restrict__ bq_l,
    const float* __restrict__ wq_r, const float* __restrict__ bq_r,
    const float* __restrict__ wv_l, const float* __restrict__ bv_l,
    const float* __restrict__ wv_r, const float* __restrict__ bv_r,
    const float* __restrict__ beta, const float* __restrict__ gamma,
    float* __restrict__ out)
{
  // LDS: 46080 + 46080 + 41984 + 13824 + 1280 + 2560 + 2560 + 1280 + 512
  //    = 156160 B  (<= 163840)
  __shared__ __align__(16) unsigned short Rs[320*RST]; // x_l raw -> Q_l -> Q_l'' -> O_r
  __shared__ __align__(16) unsigned short Ks[320*RST]; // x_r raw -> x^_r -> O_l
  __shared__ __align__(16) unsigned short Vb[64*VST];  // V_l then V_r (channel-major)
  __shared__ __align__(16) unsigned short Pt[12*16*PTS];// per-wave P->A round-trip
  __shared__ unsigned CMu[320]; // colmax as monotone uint keys (ds_max_u32)
  __shared__ float MU[640], RSd[640];  // LN stats, [0..320)=l, [320..640)=r
  __shared__ float c_arr[320];  // c_wl = 0.125 * Q_l . b~_r
  __shared__ float BB[128];     // [0..64)=b~_l, [64..128)=b~_r

  const int bh = blockIdx.x;
  const int b = bh / 180, h = bh - b*180;
  const int base = b*CHWs + h*320;

  const int t = threadIdx.x;
  const int wave = t >> 6, lane = t & 63;
  const int p = lane & 15, g = lane >> 4;
  // 20 row-tiles over 12 waves: waves 0-7 take 2, waves 8-11 take 1
  const int nwt = (wave < 8) ? 2 : 1;
  const int w0 = (wave < 8) ? wave*32 : 256 + (wave-8)*16;

  // ---------- A: staging + inline LN stats (one thread per (side,w)) ----------
  for (int w2 = t; w2 < 640; w2 += NTH) {
    const int side = (w2 >= 320);
    const int w = w2 - side*320;
    const float* xp = side ? x_r : x_l;
    unsigned short* dst = side ? Ks : Rs;
    // two sequential half-sums to match previous summation order bit-exactly
    float s0 = 0.f, q0 = 0.f, s1 = 0.f, q1 = 0.f;
    #pragma unroll
    for (int cb = 0; cb < 64; cb += 8) {
      FragU f;
      #pragma unroll
      for (int j = 0; j < 8; ++j) {
        const float v = xp[base + (cb+j)*HWs + w];
        if (cb < 32) { s0 += v; q0 += v*v; } else { s1 += v; q1 += v*v; }
        f.u[j] = f2bf(v);
      }
      *(uint4*)&dst[w*RST + cb] = f.q;
    }
    const float m  = (s0 + s1) * (1.f/64.f);
    const float vv = (q0 + q1) * (1.f/64.f) - m*m;
    MU[side*320 + w]  = m;
    RSd[side*320 + w] = rsqrtf(vv + 1e-6f);
  }
  if (t < 320) CMu[t] = 0u;   // key 0 == very negative float
  if (t < 128) {   // effective Q biases: b~ = bq + (W .* lnw) @ lnb
    const int o = t & 63;
    const float* wqp = (t < 64) ? wq_l : wq_r;
    const float* lwp = (t < 64) ? ln_l_w : ln_r_w;
    const float* lbp = (t < 64) ? ln_l_b : ln_r_b;
    const float* bqp = (t < 64) ? bq_l : bq_r;
    float s = bqp[o];
    for (int c = 0; c < 64; ++c) s += wqp[o*64+c]*lwp[c]*lbp[c];
    BB[t] = s;
  }
  __syncthreads();

  // ---------- V projection (A = Wv, B = raw x rows; all row-local) ----------
  auto projV = [&](const float* wvp, const float* bvp, const unsigned short* src,
                   const float* mup, const float* rsp, bool inv) {
    bf16x8 bx[2][2];
    #pragma unroll
    for (int nt = 0; nt < 2; ++nt) if (nt < nwt) {
      const int w = w0 + nt*16 + p;
      const float mu = mup[w];
      const float sd = inv ? (1.0f / rsp[w]) : 0.f;
      #pragma unroll
      for (int kf = 0; kf < 2; ++kf) {
        FragU f; f.q = *(const uint4*)&src[w*RST + kf*32 + g*8];
        if (inv) {           // recover raw x from normalized: x = x^*sd + mu
          FragU rr;
          #pragma unroll
          for (int j = 0; j < 8; ++j) rr.u[j] = f2bf(bf2f(f.u[j])*sd + mu);
          bx[nt][kf] = rr.v;
        } else bx[nt][kf] = f.v;
      }
    }
    bf16x8 av[4][2];
    #pragma unroll
    for (int mt = 0; mt < 4; ++mt)
      #pragma unroll
      for (int kf = 0; kf < 2; ++kf) {
        FragU rr;
        #pragma unroll
        for (int j = 0; j < 8; ++j) rr.u[j] = f2bf(wvp[(mt*16+p)*64 + kf*32 + g*8 + j]);
        av[mt][kf] = rr.v;
      }
    f32x4 acc[4][2];
    #pragma unroll
    for (int mt = 0; mt < 4; ++mt)
      #pragma unroll
      for (int nt = 0; nt < 2; ++nt) acc[mt][nt] = (f32x4){0.f,0.f,0.f,0.f};
    #pragma unroll
    for (int mt = 0; mt < 4; ++mt)
      #pragma unroll
      for (int nt = 0; nt < 2; ++nt) if (nt < nwt)
        #pragma unroll
        for (int kf = 0; kf < 2; ++kf)
          acc[mt][nt] = __builtin_amdgcn_mfma_f32_16x16x32_bf16(av[mt][kf], bx[nt][kf], acc[mt][nt], 0,0,0);
    #pragma unroll
    for (int mt = 0; mt < 4; ++mt)
      #pragma unroll
      for (int nt = 0; nt < 2; ++nt) if (nt < nwt)
        #pragma unroll
        for (int r = 0; r < 4; ++r) {
          const int o = mt*16 + g*4 + r;
          Vb[o*VST + w0 + nt*16 + p] = f2bf(acc[mt][nt][r] + bvp[o]);
        }
  };

  projV(wv_l, bv_l, Rs, MU, RSd, false);   // Vb = V_l (from raw x_l)

  // ---------- Q_l = LN(x_l) W~_l^T + b~_l  (write in place to Rs) ----------
  float cR[2][4];
  {
    bf16x8 qa[2][2];
    #pragma unroll
    for (int wt = 0; wt < 2; ++wt) if (wt < nwt) {
      const int w = w0 + wt*16 + p;
      const float mu = MU[w], rs = RSd[w];
      #pragma unroll
      for (int kf = 0; kf < 2; ++kf) {
        FragU f; f.q = *(const uint4*)&Rs[w*RST + kf*32 + g*8];
        FragU rr;
        #pragma unroll
        for (int j = 0; j < 8; ++j) rr.u[j] = f2bf((bf2f(f.u[j]) - mu) * rs);
        qa[wt][kf] = rr.v;
      }
    }
    bf16x8 bw[4][2];
    #pragma unroll
    for (int ot = 0; ot < 4; ++ot)
      #pragma unroll
      for (int kf = 0; kf < 2; ++kf) {
        FragU rr;
        #pragma unroll
        for (int j = 0; j < 8; ++j) {
          const int c = kf*32 + g*8 + j;
          rr.u[j] = f2bf(wq_l[(ot*16+p)*64 + c] * ln_l_w[c]);
        }
        bw[ot][kf] = rr.v;
      }
    f32x4 qacc[2][4];
    #pragma unroll
    for (int wt = 0; wt < 2; ++wt)
      #pragma unroll
      for (int ot = 0; ot < 4; ++ot) qacc[wt][ot] = (f32x4){0.f,0.f,0.f,0.f};
    #pragma unroll
    for (int wt = 0; wt < 2; ++wt) if (wt < nwt)
      #pragma unroll
      for (int ot = 0; ot < 4; ++ot)
        #pragma unroll
        for (int kf = 0; kf < 2; ++kf)
          qacc[wt][ot] = __builtin_amdgcn_mfma_f32_16x16x32_bf16(qa[wt][kf], bw[ot][kf], qacc[wt][ot], 0,0,0);
    // += b~_l, write Q_l, accumulate c = Q_l . b~_r
    #pragma unroll
    for (int wt = 0; wt < 2; ++wt) {
      #pragma unroll
      for (int r = 0; r < 4; ++r) cR[wt][r] = 0.f;
      if (wt < nwt) {
        #pragma unroll
        for (int ot = 0; ot < 4; ++ot) {
          const float bl = BB[ot*16+p], br = BB[64 + ot*16+p];
          #pragma unroll
          for (int r = 0; r < 4; ++r) {
            const float qv = qacc[wt][ot][r] + bl;
            Rs[(w0 + wt*16 + g*4 + r)*RST + ot*16 + p] = f2bf(qv);
            cR[wt][r] += qv * br;
          }
        }
        #pragma unroll
        for (int r = 0; r < 4; ++r) {
          float cv = cR[wt][r];
          cv += __shfl_xor(cv, 1); cv += __shfl_xor(cv, 2);
          cv += __shfl_xor(cv, 4); cv += __shfl_xor(cv, 8);
          cv *= 0.125f;
          cR[wt][r] = cv;
          if (p == 0) c_arr[w0 + wt*16 + g*4 + r] = cv;
        }
      }
    }
  }

  // ---------- Q_l'' = 0.125 * Q_l W~_r  (in place to Rs) ----------
  {
    bf16x8 qla[2][2];
    #pragma unroll
    for (int wt = 0; wt < 2; ++wt) if (wt < nwt)
      #pragma unroll
      for (int kf = 0; kf < 2; ++kf) {
        FragU f; f.q = *(const uint4*)&Rs[(w0 + wt*16 + p)*RST + kf*32 + g*8];
        qla[wt][kf] = f.v;
      }
    bf16x8 bwt[4][2];
    #pragma unroll
    for (int ct = 0; ct < 4; ++ct) {
      const float lw = ln_r_w[ct*16 + p];
      #pragma unroll
      for (int kf = 0; kf < 2; ++kf) {
        FragU rr;
        #pragma unroll
        for (int j = 0; j < 8; ++j)
          rr.u[j] = f2bf(wq_r[(kf*32 + g*8 + j)*64 + ct*16 + p] * lw);
        bwt[ct][kf] = rr.v;
      }
    }
    f32x4 q2[2][4];
    #pragma unroll
    for (int wt = 0; wt < 2; ++wt)
      #pragma unroll
      for (int ct = 0; ct < 4; ++ct) q2[wt][ct] = (f32x4){0.f,0.f,0.f,0.f};
    #pragma unroll
    for (int wt = 0; wt < 2; ++wt) if (wt < nwt)
      #pragma unroll
      for (int ct = 0; ct < 4; ++ct)
        #pragma unroll
        for (int kf = 0; kf < 2; ++kf)
          q2[wt][ct] = __builtin_amdgcn_mfma_f32_16x16x32_bf16(qla[wt][kf], bwt[ct][kf], q2[wt][ct], 0,0,0);
    #pragma unroll
    for (int wt = 0; wt < 2; ++wt) if (wt < nwt)
      #pragma unroll
      for (int ct = 0; ct < 4; ++ct)
        #pragma unroll
        for (int r = 0; r < 4; ++r)
          Rs[(w0 + wt*16 + g*4 + r)*RST + ct*16 + p] = f2bf(q2[wt][ct][r] * 0.125f);
  }

  // ---------- normalize Ks in place: x^_r = (x_r - mu) * rs ----------
  #pragma unroll
  for (int wt = 0; wt < 2; ++wt) if (wt < nwt) {
    const int w = w0 + wt*16 + p;
    const float mu = MU[320+w], rs = RSd[320+w];
    #pragma unroll
    for (int kf = 0; kf < 2; ++kf) {
      FragU f; f.q = *(const uint4*)&Ks[w*RST + kf*32 + g*8];
      FragU rr;
      #pragma unroll
      for (int j = 0; j < 8; ++j) rr.u[j] = f2bf((bf2f(f.u[j]) - mu) * rs);
      *(uint4*)&Ks[w*RST + kf*32 + g*8] = rr.q;
    }
  }
  __syncthreads();   // Rs=Q_l'', Ks=x^_r, Vb=V_l, c_arr all visible

  // ---------- persistent A-frags ----------
  bf16x8 aq[2][2], ak[2][2];
  #pragma unroll
  for (int wt = 0; wt < 2; ++wt) if (wt < nwt)
    #pragma unroll
    for (int kf = 0; kf < 2; ++kf) {
      FragU f1; f1.q = *(const uint4*)&Rs[(w0 + wt*16 + p)*RST + kf*32 + g*8];
      aq[wt][kf] = f1.v;
      FragU f2; f2.q = *(const uint4*)&Ks[(w0 + wt*16 + p)*RST + kf*32 + g*8];
      ak[wt][kf] = f2.v;
    }

  // ---------- pass 1: S stats (rowmax exact per wave; colmax via ds_max_u32) ----------
  float rm[2][4];
  #pragma unroll
  for (int wt = 0; wt < 2; ++wt)
    #pragma unroll
    for (int r = 0; r < 4; ++r) rm[wt][r] = -3.0e38f;
  for (int ch = 0; ch < 5; ++ch) {
    const int k0 = ch*64;
    bf16x8 bq[4][2];
    #pragma unroll
    for (int vt = 0; vt < 4; ++vt)
      #pragma unroll
      for (int kf = 0; kf < 2; ++kf) {
        FragU f; f.q = *(const uint4*)&Ks[(k0 + vt*16 + p)*RST + kf*32 + g*8];
        bq[vt][kf] = f.v;
      }
    f32x4 sacc[2][4];
    #pragma unroll
    for (int wt = 0; wt < 2; ++wt)
      #pragma unroll
      for (int vt = 0; vt < 4; ++vt) sacc[wt][vt] = (f32x4){0.f,0.f,0.f,0.f};
    #pragma unroll
    for (int wt = 0; wt < 2; ++wt) if (wt < nwt)
      #pragma unroll
      for (int vt = 0; vt < 4; ++vt)
        #pragma unroll
        for (int kf = 0; kf < 2; ++kf)
          sacc[wt][vt] = __builtin_amdgcn_mfma_f32_16x16x32_bf16(aq[wt][kf], bq[vt][kf], sacc[wt][vt], 0,0,0);
    #pragma unroll
    for (int wt = 0; wt < 2; ++wt) if (wt < nwt) {
      #pragma unroll
      for (int r = 0; r < 4; ++r) {
        float m4 = fmaxf(fmaxf(sacc[wt][0][r], sacc[wt][1][r]),
                         fmaxf(sacc[wt][2][r], sacc[wt][3][r])) + cR[wt][r];
        m4 = fmaxf(m4, __shfl_xor(m4, 1)); m4 = fmaxf(m4, __shfl_xor(m4, 2));
        m4 = fmaxf(m4, __shfl_xor(m4, 4)); m4 = fmaxf(m4, __shfl_xor(m4, 8));
        rm[wt][r] = fmaxf(rm[wt][r], m4);
      }
    }
    #pragma unroll
    for (int vt = 0; vt < 4; ++vt) {
      float cp = -3.0e38f;
      #pragma unroll
      for (int wt = 0; wt < 2; ++wt) if (wt < nwt)
        #pragma unroll
        for (int r = 0; r < 4; ++r) cp = fmaxf(cp, sacc[wt][vt][r] + cR[wt][r]);
      cp = fmaxf(cp, __shfl_xor(cp, 16));
      cp = fmaxf(cp, __shfl_xor(cp, 32));
      if (g == 0) atomicMax(&CMu[k0 + vt*16 + p], fenc(cp));
    }
  }
  __syncthreads();   // all colmax atomics done

  // ---------- shared attention pass (exp + row-sum + PV) ----------
  float ls[2][4];
  f32x4 oacc[2][4];
  auto attn_pass = [&](bf16x8 (&A)[2][2], const unsigned short* Bsrc,
                       float (&mx)[2][4], bool colc) {
    for (int ch = 0; ch < 5; ++ch) {
      const int k0 = ch*64;
      bf16x8 bq[4][2];
      #pragma unroll
      for (int vt = 0; vt < 4; ++vt)
        #pragma unroll
        for (int kf = 0; kf < 2; ++kf) {
          FragU f; f.q = *(const uint4*)&Bsrc[(k0 + vt*16 + p)*RST + kf*32 + g*8];
          bq[vt][kf] = f.v;
        }
      float cc4[4];
      #pragma unroll
      for (int vt = 0; vt < 4; ++vt) cc4[vt] = colc ? c_arr[k0 + vt*16 + p] : 0.f;
      f32x4 sacc[2][4];
      #pragma unroll
      for (int wt = 0; wt < 2; ++wt)
        #pragma unroll
        for (int vt = 0; vt < 4; ++vt) sacc[wt][vt] = (f32x4){0.f,0.f,0.f,0.f};
      #pragma unroll
      for (int wt = 0; wt < 2; ++wt) if (wt < nwt)
        #pragma unroll
        for (int vt = 0; vt < 4; ++vt)
          #pragma unroll
          for (int kf = 0; kf < 2; ++kf)
            sacc[wt][vt] = __builtin_amdgcn_mfma_f32_16x16x32_bf16(A[wt][kf], bq[vt][kf], sacc[wt][vt], 0,0,0);
      #pragma unroll
      for (int wt = 0; wt < 2; ++wt) if (wt < nwt) {
        #pragma unroll
        for (int r = 0; r < 4; ++r) {
          const float rc = colc ? 0.f : cR[wt][r];
          float rsum = 0.f;
          #pragma unroll
          for (int vt = 0; vt < 4; ++vt) {
            const float e = __expf(sacc[wt][vt][r] + rc + cc4[vt] - mx[wt][r]);
            sacc[wt][vt][r] = e; rsum += e;
          }
          rsum += __shfl_xor(rsum, 1); rsum += __shfl_xor(rsum, 2);
          rsum += __shfl_xor(rsum, 4); rsum += __shfl_xor(rsum, 8);
          ls[wt][r] += rsum;
        }
      }
      bf16x8 bvv[2][4];
      #pragma unroll
      for (int kf = 0; kf < 2; ++kf)
        #pragma unroll
        for (int ot = 0; ot < 4; ++ot) {
          FragU f; f.q = *(const uint4*)&Vb[(ot*16+p)*VST + k0 + kf*32 + g*8];
          bvv[kf][ot] = f.v;
        }
      unsigned short* ptw = &Pt[wave*16*PTS];
      #pragma unroll
      for (int wt = 0; wt < 2; ++wt) if (wt < nwt) {
        #pragma unroll
        for (int kf = 0; kf < 2; ++kf) {
          #pragma unroll
          for (int vh = 0; vh < 2; ++vh) {
            const int vt2 = kf*2 + vh;
            #pragma unroll
            for (int r = 0; r < 4; ++r)
              ptw[(g*4 + r)*PTS + vh*16 + p] = f2bf(sacc[wt][vt2][r]);
          }
          FragU fa; fa.q = *(const uint4*)&ptw[p*PTS + g*8];
          #pragma unroll
          for (int ot = 0; ot < 4; ++ot)
            oacc[wt][ot] = __builtin_amdgcn_mfma_f32_16x16x32_bf16(fa.v, bvv[kf][ot], oacc[wt][ot], 0,0,0);
        }
      }
    }
  };

  // ---------- pass 2b: dir1 (l->r). rows = wr, A = x^_r, B = Q_l'', V = V_l ----------
  float cmR[2][4];
  #pragma unroll
  for (int wt = 0; wt < 2; ++wt)
    #pragma unroll
    for (int r = 0; r < 4; ++r) {
      cmR[wt][r] = (wt < nwt) ? fdec(CMu[w0 + wt*16 + g*4 + r]) : 0.f;
      ls[wt][r] = 0.f;
    }
  #pragma unroll
  for (int wt = 0; wt < 2; ++wt)
    #pragma unroll
    for (int ot = 0; ot < 4; ++ot) oacc[wt][ot] = (f32x4){0.f,0.f,0.f,0.f};
  attn_pass(ak, Rs, cmR, true);
  __syncthreads();   // everyone done reading Rs (Q_l'') and Vb (V_l)

  // stash O_r -> Rs (normalized by colsum)
  #pragma unroll
  for (int wt = 0; wt < 2; ++wt) if (wt < nwt)
    #pragma unroll
    for (int r = 0; r < 4; ++r) {
      const float inv = 1.0f / ls[wt][r];
      #pragma unroll
      for (int ot = 0; ot < 4; ++ot)
        Rs[(w0 + wt*16 + g*4 + r)*RST + ot*16 + p] = f2bf(oacc[wt][ot][r] * inv);
    }

  // recompute V_r from normalized Ks (inverse LN), overwrite Vb
  projV(wv_r, bv_r, Ks, MU+320, RSd+320, true);
  __syncthreads();

  // ---------- pass 2a: dir0 (r->l). rows = wl, A = Q_l'', B = x^_r, V = V_r ----------
  #pragma unroll
  for (int wt = 0; wt < 2; ++wt)
    #pragma unroll
    for (int r = 0; r < 4; ++r) ls[wt][r] = 0.f;
  #pragma unroll
  for (int wt = 0; wt < 2; ++wt)
    #pragma unroll
    for (int ot = 0; ot < 4; ++ot) oacc[wt][ot] = (f32x4){0.f,0.f,0.f,0.f};
  attn_pass(aq, Ks, rm, false);
  __syncthreads();   // everyone done reading Ks (x^_r) and Vb (V_r)

  // stash O_l -> Ks (normalized by rowsum)
  #pragma unroll
  for (int wt = 0; wt < 2; ++wt) if (wt < nwt)
    #pragma unroll
    for (int r = 0; r < 4; ++r) {
      const float inv = 1.0f / ls[wt][r];
      #pragma unroll
      for (int ot = 0; ot < 4; ++ot)
        Ks[(w0 + wt*16 + g*4 + r)*RST + ot*16 + p] = f2bf(oacc[wt][ot][r] * inv);
    }
  __syncthreads();

  // ---------- epilogue: residual add + store, both sides (b128 row reads) ----------
  for (int w2 = t; w2 < 640; w2 += NTH) {
    const int side = (w2 >= 320);
    const int w = w2 - side*320;
    const float* xs = side ? x_r : x_l;
    const unsigned short* Osrc = side ? Rs : Ks;   // O_r in Rs, O_l in Ks
    const float* sc = side ? gamma : beta;
    float* op = out + (side ? TOTs : 0);
    #pragma unroll
    for (int cb = 0; cb < 64; cb += 8) {
      FragU f; f.q = *(const uint4*)&Osrc[w*RST + cb];
      #pragma unroll
      for (int j = 0; j < 8; ++j) {
        const int cc = cb + j;
        const int gi = base + cc*HWs + w;
        op[gi] = xs[gi] + sc[cc] * bf2f(f.u[j]);
      }
    }
  }
}

extern "C" void kernel_launch(void* const* d_in, const int* in_sizes, int n_in,
                              void* d_out, int out_size, void* d_ws, size_t ws_size,
                              hipStream_t stream) {
  (void)in_sizes; (void)n_in; (void)d_ws; (void)ws_size; (void)out_size;
  sfam_kernel<<<dim3(720), dim3(NTH), 0, stream>>>(
      (const float*)d_in[0],  (const float*)d_in[1],
      (const float*)d_in[2],  (const float*)d_in[3],
      (const float*)d_in[4],  (const float*)d_in[5],
      (const float*)d_in[6],  (const float*)d_in[7],
      (const float*)d_in[8],  (const float*)d_in[9],
      (const float*)d_in[10], (const float*)d_in[11],
      (const float*)d_in[12], (const float*)d_in[13],
      (const float*)d_in[14], (const float*)d_in[15],
      (float*)d_out);
}

// Round 4
// 426.455 us; speedup vs baseline: 1.1909x; 1.0908x over previous
//
#include <hip/hip_runtime.h>

// Fused SFAM, merged-direction kernel: one WG per (b,h) row-pair computes BOTH
// out_l and out_r. Exact two-pass softmax over the shared 320x320 score matrix
// (row stats for r->l, col stats for l->r). Key-side Q projection eliminated:
// S = (Q_l W~_r) x^_r^T + (Q_l b~_r) 1^T, so K = raw-LN x^_r.
// v4: attack the residual spill. Allocator heuristic (3 data points) allocates
// exactly 512/(2*min_waves_per_EU): (512,2)->128, (768,3)->84, (1024)->64.
// So: __launch_bounds__(768,2) -> budget 128 VGPR (fits 3 waves/SIMD: 3*128<=512),
// plus live-set restructure to bring demand ~190 -> ~140:
//  - pass 1 streams per-vt (no full sacc[2][4]/bq[4][2]); rowmax lane-reduce
//    deferred to one tree at the end
//  - attn_pass processes 32-col groups: bq2[2][2]+sa[2][2]+bvv[4]; rowsum kept
//    as per-lane partials, single lane-reduce at pass end
//  - Q/Q''/projV weight fragments streamed per output tile
//  - ak A-frags loaded just before pass 2b (not held through pass 1)
// LDS 156,160 B -> 1 WG/CU, 12 waves (8x2-tile + 4x1-tile critical path).

#define HWs  57600      // H*W
#define CHWs 3686400    // C*H*W
#define TOTs 14745600   // B*C*H*W
#define RST  72         // pixel-major row stride (ushort): 64 + 8 pad
#define VST  328        // channel-major row stride (ushort): 320 + 8 pad
#define PTS  36         // Pt row stride (ushort): 32 + 4 pad
#define NTH  768        // 12 waves

typedef short bf16x8 __attribute__((ext_vector_type(8)));
typedef float f32x4  __attribute__((ext_vector_type(4)));
union FragU { uint4 q; unsigned short u[8]; bf16x8 v; };

__device__ __forceinline__ unsigned short f2bf(float f) {
  unsigned u = __float_as_uint(f);
  u += 0x7fffu + ((u >> 16) & 1u);     // RNE
  return (unsigned short)(u >> 16);
}
__device__ __forceinline__ float bf2f(unsigned short s) {
  return __uint_as_float(((unsigned)s) << 16);
}
// monotone float<->uint keys so colmax can use native ds_max_u32
__device__ __forceinline__ unsigned fenc(float f) {
  unsigned u = __float_as_uint(f);
  return u ^ (0x80000000u | (unsigned)(-(int)(u >> 31)));
}
__device__ __forceinline__ float fdec(unsigned k) {
  return __uint_as_float(k ^ (0x80000000u | (unsigned)(-(int)((k >> 31) ^ 1u))));
}

__global__ __launch_bounds__(NTH, 2)
void sfam_kernel(
    const float* __restrict__ x_l, const float* __restrict__ x_r,
    const float* __restrict__ ln_l_w, const float* __restrict__ ln_l_b,
    const float* __restrict__ ln_r_w, const float* __restrict__ ln_r_b,
    const float* __restrict__ wq_l, const float* __restrict__ bq_l,
    const float* __restrict__ wq_r, const float* __restrict__ bq_r,
    const float* __restrict__ wv_l, const float* __restrict__ bv_l,
    const float* __restrict__ wv_r, const float* __restrict__ bv_r,
    const float* __restrict__ beta, const float* __restrict__ gamma,
    float* __restrict__ out)
{
  // LDS: 46080 + 46080 + 41984 + 13824 + 1280 + 2560 + 2560 + 1280 + 512
  //    = 156160 B  (<= 163840)
  __shared__ __align__(16) unsigned short Rs[320*RST]; // x_l raw -> Q_l -> Q_l'' -> O_r
  __shared__ __align__(16) unsigned short Ks[320*RST]; // x_r raw -> x^_r -> O_l
  __shared__ __align__(16) unsigned short Vb[64*VST];  // V_l then V_r (channel-major)
  __shared__ __align__(16) unsigned short Pt[12*16*PTS];// per-wave P->A round-trip
  __shared__ unsigned CMu[320]; // colmax as monotone uint keys (ds_max_u32)
  __shared__ float MU[640], RSd[640];  // LN stats, [0..320)=l, [320..640)=r
  __shared__ float c_arr[320];  // c_wl = 0.125 * Q_l . b~_r
  __shared__ float BB[128];     // [0..64)=b~_l, [64..128)=b~_r

  const int bh = blockIdx.x;
  const int b = bh / 180, h = bh - b*180;
  const int base = b*CHWs + h*320;

  const int t = threadIdx.x;
  const int wave = t >> 6, lane = t & 63;
  const int p = lane & 15, g = lane >> 4;
  // 20 row-tiles over 12 waves: waves 0-7 take 2, waves 8-11 take 1
  const int nwt = (wave < 8) ? 2 : 1;
  const int w0 = (wave < 8) ? wave*32 : 256 + (wave-8)*16;

  // ---------- A: staging + inline LN stats (one thread per (side,w)) ----------
  for (int w2 = t; w2 < 640; w2 += NTH) {
    const int side = (w2 >= 320);
    const int w = w2 - side*320;
    const float* xp = side ? x_r : x_l;
    unsigned short* dst = side ? Ks : Rs;
    // two sequential half-sums to match previous summation order bit-exactly
    float s0 = 0.f, q0 = 0.f, s1 = 0.f, q1 = 0.f;
    #pragma unroll
    for (int cb = 0; cb < 64; cb += 8) {
      FragU f;
      #pragma unroll
      for (int j = 0; j < 8; ++j) {
        const float v = xp[base + (cb+j)*HWs + w];
        if (cb < 32) { s0 += v; q0 += v*v; } else { s1 += v; q1 += v*v; }
        f.u[j] = f2bf(v);
      }
      *(uint4*)&dst[w*RST + cb] = f.q;
    }
    const float m  = (s0 + s1) * (1.f/64.f);
    const float vv = (q0 + q1) * (1.f/64.f) - m*m;
    MU[side*320 + w]  = m;
    RSd[side*320 + w] = rsqrtf(vv + 1e-6f);
  }
  if (t < 320) CMu[t] = 0u;   // key 0 == very negative float
  if (t < 128) {   // effective Q biases: b~ = bq + (W .* lnw) @ lnb
    const int o = t & 63;
    const float* wqp = (t < 64) ? wq_l : wq_r;
    const float* lwp = (t < 64) ? ln_l_w : ln_r_w;
    const float* lbp = (t < 64) ? ln_l_b : ln_r_b;
    const float* bqp = (t < 64) ? bq_l : bq_r;
    float s = bqp[o];
    for (int c = 0; c < 64; ++c) s += wqp[o*64+c]*lwp[c]*lbp[c];
    BB[t] = s;
  }
  __syncthreads();

  // ---------- V projection (streamed per output tile; all row-local) ----------
  auto projV = [&](const float* wvp, const float* bvp, const unsigned short* src,
                   const float* mup, const float* rsp, bool inv) {
    bf16x8 bx[2][2];
    #pragma unroll
    for (int nt = 0; nt < 2; ++nt) if (nt < nwt) {
      const int w = w0 + nt*16 + p;
      const float mu = mup[w];
      const float sd = inv ? (1.0f / rsp[w]) : 0.f;
      #pragma unroll
      for (int kf = 0; kf < 2; ++kf) {
        FragU f; f.q = *(const uint4*)&src[w*RST + kf*32 + g*8];
        if (inv) {           // recover raw x from normalized: x = x^*sd + mu
          FragU rr;
          #pragma unroll
          for (int j = 0; j < 8; ++j) rr.u[j] = f2bf(bf2f(f.u[j])*sd + mu);
          bx[nt][kf] = rr.v;
        } else bx[nt][kf] = f.v;
      }
    }
    #pragma unroll
    for (int mt = 0; mt < 4; ++mt) {
      bf16x8 av2[2];
      #pragma unroll
      for (int kf = 0; kf < 2; ++kf) {
        FragU rr;
        #pragma unroll
        for (int j = 0; j < 8; ++j) rr.u[j] = f2bf(wvp[(mt*16+p)*64 + kf*32 + g*8 + j]);
        av2[kf] = rr.v;
      }
      f32x4 acc2[2];
      #pragma unroll
      for (int nt = 0; nt < 2; ++nt) acc2[nt] = (f32x4){0.f,0.f,0.f,0.f};
      #pragma unroll
      for (int nt = 0; nt < 2; ++nt) if (nt < nwt)
        #pragma unroll
        for (int kf = 0; kf < 2; ++kf)
          acc2[nt] = __builtin_amdgcn_mfma_f32_16x16x32_bf16(av2[kf], bx[nt][kf], acc2[nt], 0,0,0);
      #pragma unroll
      for (int nt = 0; nt < 2; ++nt) if (nt < nwt)
        #pragma unroll
        for (int r = 0; r < 4; ++r) {
          const int o = mt*16 + g*4 + r;
          Vb[o*VST + w0 + nt*16 + p] = f2bf(acc2[nt][r] + bvp[o]);
        }
    }
  };

  projV(wv_l, bv_l, Rs, MU, RSd, false);   // Vb = V_l (from raw x_l)

  // ---------- Q_l = LN(x_l) W~_l^T + b~_l  (write in place to Rs) ----------
  float cR[2][4];
  {
    bf16x8 qa[2][2];
    #pragma unroll
    for (int wt = 0; wt < 2; ++wt) if (wt < nwt) {
      const int w = w0 + wt*16 + p;
      const float mu = MU[w], rs = RSd[w];
      #pragma unroll
      for (int kf = 0; kf < 2; ++kf) {
        FragU f; f.q = *(const uint4*)&Rs[w*RST + kf*32 + g*8];
        FragU rr;
        #pragma unroll
        for (int j = 0; j < 8; ++j) rr.u[j] = f2bf((bf2f(f.u[j]) - mu) * rs);
        qa[wt][kf] = rr.v;
      }
    }
    f32x4 qacc[2][4];
    #pragma unroll
    for (int wt = 0; wt < 2; ++wt)
      #pragma unroll
      for (int ot = 0; ot < 4; ++ot) qacc[wt][ot] = (f32x4){0.f,0.f,0.f,0.f};
    #pragma unroll
    for (int ot = 0; ot < 4; ++ot) {     // stream weight frags per output tile
      bf16x8 bw2[2];
      #pragma unroll
      for (int kf = 0; kf < 2; ++kf) {
        FragU rr;
        #pragma unroll
        for (int j = 0; j < 8; ++j) {
          const int c = kf*32 + g*8 + j;
          rr.u[j] = f2bf(wq_l[(ot*16+p)*64 + c] * ln_l_w[c]);
        }
        bw2[kf] = rr.v;
      }
      #pragma unroll
      for (int wt = 0; wt < 2; ++wt) if (wt < nwt)
        #pragma unroll
        for (int kf = 0; kf < 2; ++kf)
          qacc[wt][ot] = __builtin_amdgcn_mfma_f32_16x16x32_bf16(qa[wt][kf], bw2[kf], qacc[wt][ot], 0,0,0);
    }
    // += b~_l, write Q_l, accumulate c = Q_l . b~_r
    #pragma unroll
    for (int wt = 0; wt < 2; ++wt) {
      #pragma unroll
      for (int r = 0; r < 4; ++r) cR[wt][r] = 0.f;
      if (wt < nwt) {
        #pragma unroll
        for (int ot = 0; ot < 4; ++ot) {
          const float bl = BB[ot*16+p], br = BB[64 + ot*16+p];
          #pragma unroll
          for (int r = 0; r < 4; ++r) {
            const float qv = qacc[wt][ot][r] + bl;
            Rs[(w0 + wt*16 + g*4 + r)*RST + ot*16 + p] = f2bf(qv);
            cR[wt][r] += qv * br;
          }
        }
        #pragma unroll
        for (int r = 0; r < 4; ++r) {
          float cv = cR[wt][r];
          cv += __shfl_xor(cv, 1); cv += __shfl_xor(cv, 2);
          cv += __shfl_xor(cv, 4); cv += __shfl_xor(cv, 8);
          cv *= 0.125f;
          cR[wt][r] = cv;
          if (p == 0) c_arr[w0 + wt*16 + g*4 + r] = cv;
        }
      }
    }
  }

  // ---------- Q_l'' = 0.125 * Q_l W~_r  (in place to Rs) ----------
  {
    bf16x8 qla[2][2];
    #pragma unroll
    for (int wt = 0; wt < 2; ++wt) if (wt < nwt)
      #pragma unroll
      for (int kf = 0; kf < 2; ++kf) {
        FragU f; f.q = *(const uint4*)&Rs[(w0 + wt*16 + p)*RST + kf*32 + g*8];
        qla[wt][kf] = f.v;
      }
    f32x4 q2[2][4];
    #pragma unroll
    for (int wt = 0; wt < 2; ++wt)
      #pragma unroll
      for (int ct = 0; ct < 4; ++ct) q2[wt][ct] = (f32x4){0.f,0.f,0.f,0.f};
    #pragma unroll
    for (int ct = 0; ct < 4; ++ct) {     // stream transposed weight frags per ct
      const float lw = ln_r_w[ct*16 + p];
      bf16x8 bwt2[2];
      #pragma unroll
      for (int kf = 0; kf < 2; ++kf) {
        FragU rr;
        #pragma unroll
        for (int j = 0; j < 8; ++j)
          rr.u[j] = f2bf(wq_r[(kf*32 + g*8 + j)*64 + ct*16 + p] * lw);
        bwt2[kf] = rr.v;
      }
      #pragma unroll
      for (int wt = 0; wt < 2; ++wt) if (wt < nwt)
        #pragma unroll
        for (int kf = 0; kf < 2; ++kf)
          q2[wt][ct] = __builtin_amdgcn_mfma_f32_16x16x32_bf16(qla[wt][kf], bwt2[kf], q2[wt][ct], 0,0,0);
    }
    #pragma unroll
    for (int wt = 0; wt < 2; ++wt) if (wt < nwt)
      #pragma unroll
      for (int ct = 0; ct < 4; ++ct)
        #pragma unroll
        for (int r = 0; r < 4; ++r)
          Rs[(w0 + wt*16 + g*4 + r)*RST + ct*16 + p] = f2bf(q2[wt][ct][r] * 0.125f);
  }

  // ---------- normalize Ks in place: x^_r = (x_r - mu) * rs ----------
  #pragma unroll
  for (int wt = 0; wt < 2; ++wt) if (wt < nwt) {
    const int w = w0 + wt*16 + p;
    const float mu = MU[320+w], rs = RSd[320+w];
    #pragma unroll
    for (int kf = 0; kf < 2; ++kf) {
      FragU f; f.q = *(const uint4*)&Ks[w*RST + kf*32 + g*8];
      FragU rr;
      #pragma unroll
      for (int j = 0; j < 8; ++j) rr.u[j] = f2bf((bf2f(f.u[j]) - mu) * rs);
      *(uint4*)&Ks[w*RST + kf*32 + g*8] = rr.q;
    }
  }
  __syncthreads();   // Rs=Q_l'', Ks=x^_r, Vb=V_l, c_arr all visible

  // ---------- persistent A-frags: Q_l'' only (ak loaded later, pre-2b) ----------
  bf16x8 aq[2][2];
  #pragma unroll
  for (int wt = 0; wt < 2; ++wt) if (wt < nwt)
    #pragma unroll
    for (int kf = 0; kf < 2; ++kf) {
      FragU f1; f1.q = *(const uint4*)&Rs[(w0 + wt*16 + p)*RST + kf*32 + g*8];
      aq[wt][kf] = f1.v;
    }

  // ---------- pass 1: S stats, streamed per-vt (rowmax local; colmax atomics) ----------
  float rmx[2][4];
  #pragma unroll
  for (int wt = 0; wt < 2; ++wt)
    #pragma unroll
    for (int r = 0; r < 4; ++r) rmx[wt][r] = -3.0e38f;
  for (int ch = 0; ch < 5; ++ch) {
    const int k0 = ch*64;
    #pragma unroll
    for (int vt = 0; vt < 4; ++vt) {
      FragU f0, f1;
      f0.q = *(const uint4*)&Ks[(k0 + vt*16 + p)*RST + g*8];
      f1.q = *(const uint4*)&Ks[(k0 + vt*16 + p)*RST + 32 + g*8];
      f32x4 s0 = (f32x4){0.f,0.f,0.f,0.f};
      s0 = __builtin_amdgcn_mfma_f32_16x16x32_bf16(aq[0][0], f0.v, s0, 0,0,0);
      s0 = __builtin_amdgcn_mfma_f32_16x16x32_bf16(aq[0][1], f1.v, s0, 0,0,0);
      float cp = -3.0e38f;
      #pragma unroll
      for (int r = 0; r < 4; ++r) {
        const float v0 = s0[r] + cR[0][r];
        rmx[0][r] = fmaxf(rmx[0][r], v0);
        cp = fmaxf(cp, v0);
      }
      if (nwt > 1) {
        f32x4 s1 = (f32x4){0.f,0.f,0.f,0.f};
        s1 = __builtin_amdgcn_mfma_f32_16x16x32_bf16(aq[1][0], f0.v, s1, 0,0,0);
        s1 = __builtin_amdgcn_mfma_f32_16x16x32_bf16(aq[1][1], f1.v, s1, 0,0,0);
        #pragma unroll
        for (int r = 0; r < 4; ++r) {
          const float v1 = s1[r] + cR[1][r];
          rmx[1][r] = fmaxf(rmx[1][r], v1);
          cp = fmaxf(cp, v1);
        }
      }
      cp = fmaxf(cp, __shfl_xor(cp, 16));
      cp = fmaxf(cp, __shfl_xor(cp, 32));
      if (g == 0) atomicMax(&CMu[k0 + vt*16 + p], fenc(cp));
    }
  }
  float rm[2][4];   // one lane-reduce tree at the end (max is order-insensitive)
  #pragma unroll
  for (int wt = 0; wt < 2; ++wt)
    #pragma unroll
    for (int r = 0; r < 4; ++r) {
      float m = rmx[wt][r];
      m = fmaxf(m, __shfl_xor(m, 1)); m = fmaxf(m, __shfl_xor(m, 2));
      m = fmaxf(m, __shfl_xor(m, 4)); m = fmaxf(m, __shfl_xor(m, 8));
      rm[wt][r] = m;
    }
  __syncthreads();   // all colmax atomics done

  // ---------- shared attention pass (exp + row-sum + PV), 32-col groups ----------
  float ls[2][4];
  f32x4 oacc[2][4];
  auto attn_pass = [&](bf16x8 (&A)[2][2], const unsigned short* Bsrc,
                       float (&mx)[2][4], bool colc) {
    float rsa[2][4];   // per-lane rowsum partials; one lane-reduce at the end
    #pragma unroll
    for (int wt = 0; wt < 2; ++wt)
      #pragma unroll
      for (int r = 0; r < 4; ++r) rsa[wt][r] = 0.f;
    unsigned short* ptw = &Pt[wave*16*PTS];
    for (int ch = 0; ch < 5; ++ch) {
      const int k0 = ch*64;
      #pragma unroll
      for (int pvk = 0; pvk < 2; ++pvk) {   // 32 score-cols at a time
        bf16x8 bq2[2][2];
        #pragma unroll
        for (int vh = 0; vh < 2; ++vh)
          #pragma unroll
          for (int kf = 0; kf < 2; ++kf) {
            FragU f; f.q = *(const uint4*)&Bsrc[(k0 + (pvk*2+vh)*16 + p)*RST + kf*32 + g*8];
            bq2[vh][kf] = f.v;
          }
        float cc2[2];
        #pragma unroll
        for (int vh = 0; vh < 2; ++vh)
          cc2[vh] = colc ? c_arr[k0 + (pvk*2+vh)*16 + p] : 0.f;
        f32x4 sa[2][2];
        #pragma unroll
        for (int wt = 0; wt < 2; ++wt)
          #pragma unroll
          for (int vh = 0; vh < 2; ++vh) sa[wt][vh] = (f32x4){0.f,0.f,0.f,0.f};
        #pragma unroll
        for (int wt = 0; wt < 2; ++wt) if (wt < nwt)
          #pragma unroll
          for (int vh = 0; vh < 2; ++vh)
            #pragma unroll
            for (int kf = 0; kf < 2; ++kf)
              sa[wt][vh] = __builtin_amdgcn_mfma_f32_16x16x32_bf16(A[wt][kf], bq2[vh][kf], sa[wt][vh], 0,0,0);
        #pragma unroll
        for (int wt = 0; wt < 2; ++wt) if (wt < nwt) {
          #pragma unroll
          for (int r = 0; r < 4; ++r) {
            const float rc = colc ? 0.f : cR[wt][r];
            #pragma unroll
            for (int vh = 0; vh < 2; ++vh) {
              const float e = __expf(sa[wt][vh][r] + rc + cc2[vh] - mx[wt][r]);
              sa[wt][vh][r] = e;
              rsa[wt][r] += e;
            }
          }
        }
        bf16x8 bvv[4];
        #pragma unroll
        for (int ot = 0; ot < 4; ++ot) {
          FragU f; f.q = *(const uint4*)&Vb[(ot*16+p)*VST + k0 + pvk*32 + g*8];
          bvv[ot] = f.v;
        }
        #pragma unroll
        for (int wt = 0; wt < 2; ++wt) if (wt < nwt) {
          #pragma unroll
          for (int vh = 0; vh < 2; ++vh)
            #pragma unroll
            for (int r = 0; r < 4; ++r)
              ptw[(g*4 + r)*PTS + vh*16 + p] = f2bf(sa[wt][vh][r]);
          FragU fa; fa.q = *(const uint4*)&ptw[p*PTS + g*8];
          #pragma unroll
          for (int ot = 0; ot < 4; ++ot)
            oacc[wt][ot] = __builtin_amdgcn_mfma_f32_16x16x32_bf16(fa.v, bvv[ot], oacc[wt][ot], 0,0,0);
        }
      }
    }
    #pragma unroll
    for (int wt = 0; wt < 2; ++wt)
      #pragma unroll
      for (int r = 0; r < 4; ++r) {
        float s = rsa[wt][r];
        s += __shfl_xor(s, 1); s += __shfl_xor(s, 2);
        s += __shfl_xor(s, 4); s += __shfl_xor(s, 8);
        ls[wt][r] = s;
      }
  };

  // ---------- pass 2b: dir1 (l->r). rows = wr, A = x^_r, B = Q_l'', V = V_l ----------
  bf16x8 ak[2][2];   // loaded here, not held through pass 1
  #pragma unroll
  for (int wt = 0; wt < 2; ++wt) if (wt < nwt)
    #pragma unroll
    for (int kf = 0; kf < 2; ++kf) {
      FragU f2; f2.q = *(const uint4*)&Ks[(w0 + wt*16 + p)*RST + kf*32 + g*8];
      ak[wt][kf] = f2.v;
    }
  float cmR[2][4];
  #pragma unroll
  for (int wt = 0; wt < 2; ++wt)
    #pragma unroll
    for (int r = 0; r < 4; ++r)
      cmR[wt][r] = (wt < nwt) ? fdec(CMu[w0 + wt*16 + g*4 + r]) : 0.f;
  #pragma unroll
  for (int wt = 0; wt < 2; ++wt)
    #pragma unroll
    for (int ot = 0; ot < 4; ++ot) oacc[wt][ot] = (f32x4){0.f,0.f,0.f,0.f};
  attn_pass(ak, Rs, cmR, true);
  __syncthreads();   // everyone done reading Rs (Q_l'') and Vb (V_l)

  // stash O_r -> Rs (normalized by colsum)
  #pragma unroll
  for (int wt = 0; wt < 2; ++wt) if (wt < nwt)
    #pragma unroll
    for (int r = 0; r < 4; ++r) {
      const float inv = 1.0f / ls[wt][r];
      #pragma unroll
      for (int ot = 0; ot < 4; ++ot)
        Rs[(w0 + wt*16 + g*4 + r)*RST + ot*16 + p] = f2bf(oacc[wt][ot][r] * inv);
    }

  // recompute V_r from normalized Ks (inverse LN), overwrite Vb
  projV(wv_r, bv_r, Ks, MU+320, RSd+320, true);
  __syncthreads();

  // ---------- pass 2a: dir0 (r->l). rows = wl, A = Q_l'', B = x^_r, V = V_r ----------
  #pragma unroll
  for (int wt = 0; wt < 2; ++wt)
    #pragma unroll
    for (int ot = 0; ot < 4; ++ot) oacc[wt][ot] = (f32x4){0.f,0.f,0.f,0.f};
  attn_pass(aq, Ks, rm, false);
  __syncthreads();   // everyone done reading Ks (x^_r) and Vb (V_r)

  // stash O_l -> Ks (normalized by rowsum)
  #pragma unroll
  for (int wt = 0; wt < 2; ++wt) if (wt < nwt)
    #pragma unroll
    for (int r = 0; r < 4; ++r) {
      const float inv = 1.0f / ls[wt][r];
      #pragma unroll
      for (int ot = 0; ot < 4; ++ot)
        Ks[(w0 + wt*16 + g*4 + r)*RST + ot*16 + p] = f2bf(oacc[wt][ot][r] * inv);
    }
  __syncthreads();

  // ---------- epilogue: residual add + store, both sides (b128 row reads) ----------
  for (int w2 = t; w2 < 640; w2 += NTH) {
    const int side = (w2 >= 320);
    const int w = w2 - side*320;
    const float* xs = side ? x_r : x_l;
    const unsigned short* Osrc = side ? Rs : Ks;   // O_r in Rs, O_l in Ks
    const float* sc = side ? gamma : beta;
    float* op = out + (side ? TOTs : 0);
    #pragma unroll
    for (int cb = 0; cb < 64; cb += 8) {
      FragU f; f.q = *(const uint4*)&Osrc[w*RST + cb];
      #pragma unroll
      for (int j = 0; j < 8; ++j) {
        const int cc = cb + j;
        const int gi = base + cc*HWs + w;
        op[gi] = xs[gi] + sc[cc] * bf2f(f.u[j]);
      }
    }
  }
}

extern "C" void kernel_launch(void* const* d_in, const int* in_sizes, int n_in,
                              void* d_out, int out_size, void* d_ws, size_t ws_size,
                              hipStream_t stream) {
  (void)in_sizes; (void)n_in; (void)d_ws; (void)ws_size; (void)out_size;
  sfam_kernel<<<dim3(720), dim3(NTH), 0, stream>>>(
      (const float*)d_in[0],  (const float*)d_in[1],
      (const float*)d_in[2],  (const float*)d_in[3],
      (const float*)d_in[4],  (const float*)d_in[5],
      (const float*)d_in[6],  (const float*)d_in[7],
      (const float*)d_in[8],  (const float*)d_in[9],
      (const float*)d_in[10], (const float*)d_in[11],
      (const float*)d_in[12], (const float*)d_in[13],
      (const float*)d_in[14], (const float*)d_in[15],
      (float*)d_out);
}

// Round 5
// 416.118 us; speedup vs baseline: 1.2205x; 1.0248x over previous
//
#include <hip/hip_runtime.h>

// Fused SFAM, merged-direction kernel: one WG per (b,h) row-pair computes BOTH
// out_l and out_r. Key-side Q projection eliminated:
// S = (Q_l W~_r) x^_r^T + (Q_l b~_r) 1^T, so K = raw-LN x^_r.
// v5: ELIMINATE pass 1 (exact S stats). Softmax is shift-invariant for any
// M >= rowmax (values scale by e^-delta; fp is scale-free; underflow needs
// delta>80). Use Cauchy-Schwarz bounds instead of exact maxes:
//   dir0 (rows=wl, reduce over wr):  M_wl = ||Q''_wl|| * NXmax   (cR cancels)
//   dir1 (rows=wr, reduce over wl):  M_wr = nx_wr * Qnmax + Cmax
// where nx_j = ||x^_r_j|| = 8*sqrt(v/(v+eps)) comes FREE from the LN stats in
// staging, row norms ||Q''|| are computed in-register at Q'' time, and
// Qnmax/Cmax/NXmax are single-scalar LDS atomicMax reductions.
// Deletes per heavy wave: 80 MFMAs (25% of attn MFMA), 40 b128 LDS reads,
// 20 atomic+shuffle chains, one barrier, the CMu buffer.
// Carried from v4: 768 thr = 12 waves, launch_bounds(768,2), streamed weight
// frags, 32-col attn groups, per-lane rowsum partials. LDS ~156 KB, 1 WG/CU.

#define HWs  57600      // H*W
#define CHWs 3686400    // C*H*W
#define TOTs 14745600   // B*C*H*W
#define RST  72         // pixel-major row stride (ushort): 64 + 8 pad
#define VST  328        // channel-major row stride (ushort): 320 + 8 pad
#define PTS  36         // Pt row stride (ushort): 32 + 4 pad
#define NTH  768        // 12 waves

typedef short bf16x8 __attribute__((ext_vector_type(8)));
typedef float f32x4  __attribute__((ext_vector_type(4)));
union FragU { uint4 q; unsigned short u[8]; bf16x8 v; };

__device__ __forceinline__ unsigned short f2bf(float f) {
  unsigned u = __float_as_uint(f);
  u += 0x7fffu + ((u >> 16) & 1u);     // RNE
  return (unsigned short)(u >> 16);
}
__device__ __forceinline__ float bf2f(unsigned short s) {
  return __uint_as_float(((unsigned)s) << 16);
}
// monotone float<->uint keys so max-reductions can use native ds_max_u32
__device__ __forceinline__ unsigned fenc(float f) {
  unsigned u = __float_as_uint(f);
  return u ^ (0x80000000u | (unsigned)(-(int)(u >> 31)));
}
__device__ __forceinline__ float fdec(unsigned k) {
  return __uint_as_float(k ^ (0x80000000u | (unsigned)(-(int)((k >> 31) ^ 1u))));
}

__global__ __launch_bounds__(NTH, 2)
void sfam_kernel(
    const float* __restrict__ x_l, const float* __restrict__ x_r,
    const float* __restrict__ ln_l_w, const float* __restrict__ ln_l_b,
    const float* __restrict__ ln_r_w, const float* __restrict__ ln_r_b,
    const float* __restrict__ wq_l, const float* __restrict__ bq_l,
    const float* __restrict__ wq_r, const float* __restrict__ bq_r,
    const float* __restrict__ wv_l, const float* __restrict__ bv_l,
    const float* __restrict__ wv_r, const float* __restrict__ bv_r,
    const float* __restrict__ beta, const float* __restrict__ gamma,
    float* __restrict__ out)
{
  // LDS: 46080 + 46080 + 41984 + 13824 + 1280(NX) + 2560 + 2560 + 1280 + 512
  //      + 12(SCu) ~= 156,172 B  (<= 163840)
  __shared__ __align__(16) unsigned short Rs[320*RST]; // x_l raw -> Q_l -> Q_l'' -> O_r
  __shared__ __align__(16) unsigned short Ks[320*RST]; // x_r raw -> x^_r -> O_l
  __shared__ __align__(16) unsigned short Vb[64*VST];  // V_l then V_r (channel-major)
  __shared__ __align__(16) unsigned short Pt[12*16*PTS];// per-wave P->A round-trip
  __shared__ float NX[320];     // ||x^_r_j|| per side-r row
  __shared__ float MU[640], RSd[640];  // LN stats, [0..320)=l, [320..640)=r
  __shared__ float c_arr[320];  // c_wl = 0.125 * Q_l . b~_r
  __shared__ float BB[128];     // [0..64)=b~_l, [64..128)=b~_r
  __shared__ unsigned SCu[3];   // monotone-key maxes: [0]=NXmax [1]=Qn^2max [2]=Cmax

  const int bh = blockIdx.x;
  const int b = bh / 180, h = bh - b*180;
  const int base = b*CHWs + h*320;

  const int t = threadIdx.x;
  const int wave = t >> 6, lane = t & 63;
  const int p = lane & 15, g = lane >> 4;
  // 20 row-tiles over 12 waves: waves 0-7 take 2, waves 8-11 take 1
  const int nwt = (wave < 8) ? 2 : 1;
  const int w0 = (wave < 8) ? wave*32 : 256 + (wave-8)*16;

  if (t < 3) SCu[t] = 0u;   // key 0 is below every real float key

  // ---------- A: staging + inline LN stats (one thread per (side,w)) ----------
  for (int w2 = t; w2 < 640; w2 += NTH) {
    const int side = (w2 >= 320);
    const int w = w2 - side*320;
    const float* xp = side ? x_r : x_l;
    unsigned short* dst = side ? Ks : Rs;
    // two sequential half-sums to match previous summation order bit-exactly
    float s0 = 0.f, q0 = 0.f, s1 = 0.f, q1 = 0.f;
    #pragma unroll
    for (int cb = 0; cb < 64; cb += 8) {
      FragU f;
      #pragma unroll
      for (int j = 0; j < 8; ++j) {
        const float v = xp[base + (cb+j)*HWs + w];
        if (cb < 32) { s0 += v; q0 += v*v; } else { s1 += v; q1 += v*v; }
        f.u[j] = f2bf(v);
      }
      *(uint4*)&dst[w*RST + cb] = f.q;
    }
    const float m  = (s0 + s1) * (1.f/64.f);
    const float vv = (q0 + q1) * (1.f/64.f) - m*m;
    MU[side*320 + w]  = m;
    RSd[side*320 + w] = rsqrtf(vv + 1e-6f);
    if (side) {   // ||x^_r|| = 8*sqrt(v/(v+eps)) -- free from LN stats
      const float vc = fmaxf(vv, 0.f);
      const float nx = 8.f * sqrtf(vc / (vc + 1e-6f));
      NX[w] = nx;
      atomicMax(&SCu[0], fenc(nx));
    }
  }
  if (t < 128) {   // effective Q biases: b~ = bq + (W .* lnw) @ lnb
    const int o = t & 63;
    const float* wqp = (t < 64) ? wq_l : wq_r;
    const float* lwp = (t < 64) ? ln_l_w : ln_r_w;
    const float* lbp = (t < 64) ? ln_l_b : ln_r_b;
    const float* bqp = (t < 64) ? bq_l : bq_r;
    float s = bqp[o];
    for (int c = 0; c < 64; ++c) s += wqp[o*64+c]*lwp[c]*lbp[c];
    BB[t] = s;
  }
  __syncthreads();

  // ---------- V projection (streamed per output tile; all row-local) ----------
  auto projV = [&](const float* wvp, const float* bvp, const unsigned short* src,
                   const float* mup, const float* rsp, bool inv) {
    bf16x8 bx[2][2];
    #pragma unroll
    for (int nt = 0; nt < 2; ++nt) if (nt < nwt) {
      const int w = w0 + nt*16 + p;
      const float mu = mup[w];
      const float sd = inv ? (1.0f / rsp[w]) : 0.f;
      #pragma unroll
      for (int kf = 0; kf < 2; ++kf) {
        FragU f; f.q = *(const uint4*)&src[w*RST + kf*32 + g*8];
        if (inv) {           // recover raw x from normalized: x = x^*sd + mu
          FragU rr;
          #pragma unroll
          for (int j = 0; j < 8; ++j) rr.u[j] = f2bf(bf2f(f.u[j])*sd + mu);
          bx[nt][kf] = rr.v;
        } else bx[nt][kf] = f.v;
      }
    }
    #pragma unroll
    for (int mt = 0; mt < 4; ++mt) {
      bf16x8 av2[2];
      #pragma unroll
      for (int kf = 0; kf < 2; ++kf) {
        FragU rr;
        #pragma unroll
        for (int j = 0; j < 8; ++j) rr.u[j] = f2bf(wvp[(mt*16+p)*64 + kf*32 + g*8 + j]);
        av2[kf] = rr.v;
      }
      f32x4 acc2[2];
      #pragma unroll
      for (int nt = 0; nt < 2; ++nt) acc2[nt] = (f32x4){0.f,0.f,0.f,0.f};
      #pragma unroll
      for (int nt = 0; nt < 2; ++nt) if (nt < nwt)
        #pragma unroll
        for (int kf = 0; kf < 2; ++kf)
          acc2[nt] = __builtin_amdgcn_mfma_f32_16x16x32_bf16(av2[kf], bx[nt][kf], acc2[nt], 0,0,0);
      #pragma unroll
      for (int nt = 0; nt < 2; ++nt) if (nt < nwt)
        #pragma unroll
        for (int r = 0; r < 4; ++r) {
          const int o = mt*16 + g*4 + r;
          Vb[o*VST + w0 + nt*16 + p] = f2bf(acc2[nt][r] + bvp[o]);
        }
    }
  };

  projV(wv_l, bv_l, Rs, MU, RSd, false);   // Vb = V_l (from raw x_l)

  // ---------- Q_l = LN(x_l) W~_l^T + b~_l  (write in place to Rs) ----------
  float cR[2][4];
  {
    bf16x8 qa[2][2];
    #pragma unroll
    for (int wt = 0; wt < 2; ++wt) if (wt < nwt) {
      const int w = w0 + wt*16 + p;
      const float mu = MU[w], rs = RSd[w];
      #pragma unroll
      for (int kf = 0; kf < 2; ++kf) {
        FragU f; f.q = *(const uint4*)&Rs[w*RST + kf*32 + g*8];
        FragU rr;
        #pragma unroll
        for (int j = 0; j < 8; ++j) rr.u[j] = f2bf((bf2f(f.u[j]) - mu) * rs);
        qa[wt][kf] = rr.v;
      }
    }
    f32x4 qacc[2][4];
    #pragma unroll
    for (int wt = 0; wt < 2; ++wt)
      #pragma unroll
      for (int ot = 0; ot < 4; ++ot) qacc[wt][ot] = (f32x4){0.f,0.f,0.f,0.f};
    #pragma unroll
    for (int ot = 0; ot < 4; ++ot) {     // stream weight frags per output tile
      bf16x8 bw2[2];
      #pragma unroll
      for (int kf = 0; kf < 2; ++kf) {
        FragU rr;
        #pragma unroll
        for (int j = 0; j < 8; ++j) {
          const int c = kf*32 + g*8 + j;
          rr.u[j] = f2bf(wq_l[(ot*16+p)*64 + c] * ln_l_w[c]);
        }
        bw2[kf] = rr.v;
      }
      #pragma unroll
      for (int wt = 0; wt < 2; ++wt) if (wt < nwt)
        #pragma unroll
        for (int kf = 0; kf < 2; ++kf)
          qacc[wt][ot] = __builtin_amdgcn_mfma_f32_16x16x32_bf16(qa[wt][kf], bw2[kf], qacc[wt][ot], 0,0,0);
    }
    // += b~_l, write Q_l, accumulate c = Q_l . b~_r
    #pragma unroll
    for (int wt = 0; wt < 2; ++wt) {
      #pragma unroll
      for (int r = 0; r < 4; ++r) cR[wt][r] = 0.f;
      if (wt < nwt) {
        #pragma unroll
        for (int ot = 0; ot < 4; ++ot) {
          const float bl = BB[ot*16+p], br = BB[64 + ot*16+p];
          #pragma unroll
          for (int r = 0; r < 4; ++r) {
            const float qv = qacc[wt][ot][r] + bl;
            Rs[(w0 + wt*16 + g*4 + r)*RST + ot*16 + p] = f2bf(qv);
            cR[wt][r] += qv * br;
          }
        }
        #pragma unroll
        for (int r = 0; r < 4; ++r) {
          float cv = cR[wt][r];
          cv += __shfl_xor(cv, 1); cv += __shfl_xor(cv, 2);
          cv += __shfl_xor(cv, 4); cv += __shfl_xor(cv, 8);
          cv *= 0.125f;
          cR[wt][r] = cv;
          if (p == 0) {
            c_arr[w0 + wt*16 + g*4 + r] = cv;
            atomicMax(&SCu[2], fenc(cv));
          }
        }
      }
    }
  }

  // ---------- Q_l'' = 0.125 * Q_l W~_r (in place to Rs) + row norms ----------
  float rm[2][4];   // dir0 softmax shift: ||Q''_row|| * NXmax  (cR cancels)
  {
    bf16x8 qla[2][2];
    #pragma unroll
    for (int wt = 0; wt < 2; ++wt) if (wt < nwt)
      #pragma unroll
      for (int kf = 0; kf < 2; ++kf) {
        FragU f; f.q = *(const uint4*)&Rs[(w0 + wt*16 + p)*RST + kf*32 + g*8];
        qla[wt][kf] = f.v;
      }
    f32x4 q2[2][4];
    #pragma unroll
    for (int wt = 0; wt < 2; ++wt)
      #pragma unroll
      for (int ct = 0; ct < 4; ++ct) q2[wt][ct] = (f32x4){0.f,0.f,0.f,0.f};
    #pragma unroll
    for (int ct = 0; ct < 4; ++ct) {     // stream transposed weight frags per ct
      const float lw = ln_r_w[ct*16 + p];
      bf16x8 bwt2[2];
      #pragma unroll
      for (int kf = 0; kf < 2; ++kf) {
        FragU rr;
        #pragma unroll
        for (int j = 0; j < 8; ++j)
          rr.u[j] = f2bf(wq_r[(kf*32 + g*8 + j)*64 + ct*16 + p] * lw);
        bwt2[kf] = rr.v;
      }
      #pragma unroll
      for (int wt = 0; wt < 2; ++wt) if (wt < nwt)
        #pragma unroll
        for (int kf = 0; kf < 2; ++kf)
          q2[wt][ct] = __builtin_amdgcn_mfma_f32_16x16x32_bf16(qla[wt][kf], bwt2[kf], q2[wt][ct], 0,0,0);
    }
    const float NXmax = fdec(SCu[0]);   // final since staging barrier
    #pragma unroll
    for (int wt = 0; wt < 2; ++wt) {
      #pragma unroll
      for (int r = 0; r < 4; ++r) rm[wt][r] = 0.f;
      if (wt < nwt) {
        #pragma unroll
        for (int r = 0; r < 4; ++r) {
          float qsq = 0.f;
          #pragma unroll
          for (int ct = 0; ct < 4; ++ct) {
            const float qv = q2[wt][ct][r] * 0.125f;
            Rs[(w0 + wt*16 + g*4 + r)*RST + ct*16 + p] = f2bf(qv);
            qsq += qv*qv;
          }
          qsq += __shfl_xor(qsq, 1); qsq += __shfl_xor(qsq, 2);
          qsq += __shfl_xor(qsq, 4); qsq += __shfl_xor(qsq, 8);
          rm[wt][r] = sqrtf(qsq) * NXmax;
          if (p == 0) atomicMax(&SCu[1], fenc(qsq));
        }
      }
    }
  }

  // ---------- normalize Ks in place: x^_r = (x_r - mu) * rs ----------
  #pragma unroll
  for (int wt = 0; wt < 2; ++wt) if (wt < nwt) {
    const int w = w0 + wt*16 + p;
    const float mu = MU[320+w], rs = RSd[320+w];
    #pragma unroll
    for (int kf = 0; kf < 2; ++kf) {
      FragU f; f.q = *(const uint4*)&Ks[w*RST + kf*32 + g*8];
      FragU rr;
      #pragma unroll
      for (int j = 0; j < 8; ++j) rr.u[j] = f2bf((bf2f(f.u[j]) - mu) * rs);
      *(uint4*)&Ks[w*RST + kf*32 + g*8] = rr.q;
    }
  }
  __syncthreads();   // Rs=Q_l'', Ks=x^_r, Vb=V_l, c_arr, SCu all visible

  // ---------- persistent A-frags: Q_l'' (for 2a) ----------
  bf16x8 aq[2][2];
  #pragma unroll
  for (int wt = 0; wt < 2; ++wt) if (wt < nwt)
    #pragma unroll
    for (int kf = 0; kf < 2; ++kf) {
      FragU f1; f1.q = *(const uint4*)&Rs[(w0 + wt*16 + p)*RST + kf*32 + g*8];
      aq[wt][kf] = f1.v;
    }

  // ---------- shared attention pass (exp + row-sum + PV), 32-col groups ----------
  float ls[2][4];
  f32x4 oacc[2][4];
  auto attn_pass = [&](bf16x8 (&A)[2][2], const unsigned short* Bsrc,
                       float (&mx)[2][4], bool colc) {
    float rsa[2][4];   // per-lane rowsum partials; one lane-reduce at the end
    #pragma unroll
    for (int wt = 0; wt < 2; ++wt)
      #pragma unroll
      for (int r = 0; r < 4; ++r) rsa[wt][r] = 0.f;
    unsigned short* ptw = &Pt[wave*16*PTS];
    for (int ch = 0; ch < 5; ++ch) {
      const int k0 = ch*64;
      #pragma unroll
      for (int pvk = 0; pvk < 2; ++pvk) {   // 32 score-cols at a time
        bf16x8 bq2[2][2];
        #pragma unroll
        for (int vh = 0; vh < 2; ++vh)
          #pragma unroll
          for (int kf = 0; kf < 2; ++kf) {
            FragU f; f.q = *(const uint4*)&Bsrc[(k0 + (pvk*2+vh)*16 + p)*RST + kf*32 + g*8];
            bq2[vh][kf] = f.v;
          }
        float cc2[2];
        #pragma unroll
        for (int vh = 0; vh < 2; ++vh)
          cc2[vh] = colc ? c_arr[k0 + (pvk*2+vh)*16 + p] : 0.f;
        f32x4 sa[2][2];
        #pragma unroll
        for (int wt = 0; wt < 2; ++wt)
          #pragma unroll
          for (int vh = 0; vh < 2; ++vh) sa[wt][vh] = (f32x4){0.f,0.f,0.f,0.f};
        #pragma unroll
        for (int wt = 0; wt < 2; ++wt) if (wt < nwt)
          #pragma unroll
          for (int vh = 0; vh < 2; ++vh)
            #pragma unroll
            for (int kf = 0; kf < 2; ++kf)
              sa[wt][vh] = __builtin_amdgcn_mfma_f32_16x16x32_bf16(A[wt][kf], bq2[vh][kf], sa[wt][vh], 0,0,0);
        #pragma unroll
        for (int wt = 0; wt < 2; ++wt) if (wt < nwt) {
          #pragma unroll
          for (int r = 0; r < 4; ++r) {
            #pragma unroll
            for (int vh = 0; vh < 2; ++vh) {
              const float e = __expf(sa[wt][vh][r] + cc2[vh] - mx[wt][r]);
              sa[wt][vh][r] = e;
              rsa[wt][r] += e;
            }
          }
        }
        bf16x8 bvv[4];
        #pragma unroll
        for (int ot = 0; ot < 4; ++ot) {
          FragU f; f.q = *(const uint4*)&Vb[(ot*16+p)*VST + k0 + pvk*32 + g*8];
          bvv[ot] = f.v;
        }
        #pragma unroll
        for (int wt = 0; wt < 2; ++wt) if (wt < nwt) {
          #pragma unroll
          for (int vh = 0; vh < 2; ++vh)
            #pragma unroll
            for (int r = 0; r < 4; ++r)
              ptw[(g*4 + r)*PTS + vh*16 + p] = f2bf(sa[wt][vh][r]);
          FragU fa; fa.q = *(const uint4*)&ptw[p*PTS + g*8];
          #pragma unroll
          for (int ot = 0; ot < 4; ++ot)
            oacc[wt][ot] = __builtin_amdgcn_mfma_f32_16x16x32_bf16(fa.v, bvv[ot], oacc[wt][ot], 0,0,0);
        }
      }
    }
    #pragma unroll
    for (int wt = 0; wt < 2; ++wt)
      #pragma unroll
      for (int r = 0; r < 4; ++r) {
        float s = rsa[wt][r];
        s += __shfl_xor(s, 1); s += __shfl_xor(s, 2);
        s += __shfl_xor(s, 4); s += __shfl_xor(s, 8);
        ls[wt][r] = s;
      }
  };

  // ---------- pass 2b: dir1 (l->r). rows = wr, A = x^_r, B = Q_l'', V = V_l ----------
  bf16x8 ak[2][2];   // loaded here, not held earlier
  #pragma unroll
  for (int wt = 0; wt < 2; ++wt) if (wt < nwt)
    #pragma unroll
    for (int kf = 0; kf < 2; ++kf) {
      FragU f2; f2.q = *(const uint4*)&Ks[(w0 + wt*16 + p)*RST + kf*32 + g*8];
      ak[wt][kf] = f2.v;
    }
  float cmR[2][4];   // dir1 shift: nx_wr * Qnmax + Cmax
  {
    const float Qnmax = sqrtf(fdec(SCu[1]));
    const float Cmax  = fdec(SCu[2]);
    #pragma unroll
    for (int wt = 0; wt < 2; ++wt)
      #pragma unroll
      for (int r = 0; r < 4; ++r)
        cmR[wt][r] = (wt < nwt) ? NX[w0 + wt*16 + g*4 + r] * Qnmax + Cmax : 0.f;
  }
  #pragma unroll
  for (int wt = 0; wt < 2; ++wt)
    #pragma unroll
    for (int ot = 0; ot < 4; ++ot) oacc[wt][ot] = (f32x4){0.f,0.f,0.f,0.f};
  attn_pass(ak, Rs, cmR, true);
  __syncthreads();   // everyone done reading Rs (Q_l'') and Vb (V_l)

  // stash O_r -> Rs (normalized by colsum)
  #pragma unroll
  for (int wt = 0; wt < 2; ++wt) if (wt < nwt)
    #pragma unroll
    for (int r = 0; r < 4; ++r) {
      const float inv = 1.0f / ls[wt][r];
      #pragma unroll
      for (int ot = 0; ot < 4; ++ot)
        Rs[(w0 + wt*16 + g*4 + r)*RST + ot*16 + p] = f2bf(oacc[wt][ot][r] * inv);
    }

  // recompute V_r from normalized Ks (inverse LN), overwrite Vb
  projV(wv_r, bv_r, Ks, MU+320, RSd+320, true);
  __syncthreads();

  // ---------- pass 2a: dir0 (r->l). rows = wl, A = Q_l'', B = x^_r, V = V_r ----------
  #pragma unroll
  for (int wt = 0; wt < 2; ++wt)
    #pragma unroll
    for (int ot = 0; ot < 4; ++ot) oacc[wt][ot] = (f32x4){0.f,0.f,0.f,0.f};
  attn_pass(aq, Ks, rm, false);
  __syncthreads();   // everyone done reading Ks (x^_r) and Vb (V_r)

  // stash O_l -> Ks (normalized by rowsum)
  #pragma unroll
  for (int wt = 0; wt < 2; ++wt) if (wt < nwt)
    #pragma unroll
    for (int r = 0; r < 4; ++r) {
      const float inv = 1.0f / ls[wt][r];
      #pragma unroll
      for (int ot = 0; ot < 4; ++ot)
        Ks[(w0 + wt*16 + g*4 + r)*RST + ot*16 + p] = f2bf(oacc[wt][ot][r] * inv);
    }
  __syncthreads();

  // ---------- epilogue: residual add + store, both sides (b128 row reads) ----------
  for (int w2 = t; w2 < 640; w2 += NTH) {
    const int side = (w2 >= 320);
    const int w = w2 - side*320;
    const float* xs = side ? x_r : x_l;
    const unsigned short* Osrc = side ? Rs : Ks;   // O_r in Rs, O_l in Ks
    const float* sc = side ? gamma : beta;
    float* op = out + (side ? TOTs : 0);
    #pragma unroll
    for (int cb = 0; cb < 64; cb += 8) {
      FragU f; f.q = *(const uint4*)&Osrc[w*RST + cb];
      #pragma unroll
      for (int j = 0; j < 8; ++j) {
        const int cc = cb + j;
        const int gi = base + cc*HWs + w;
        op[gi] = xs[gi] + sc[cc] * bf2f(f.u[j]);
      }
    }
  }
}

extern "C" void kernel_launch(void* const* d_in, const int* in_sizes, int n_in,
                              void* d_out, int out_size, void* d_ws, size_t ws_size,
                              hipStream_t stream) {
  (void)in_sizes; (void)n_in; (void)d_ws; (void)ws_size; (void)out_size;
  sfam_kernel<<<dim3(720), dim3(NTH), 0, stream>>>(
      (const float*)d_in[0],  (const float*)d_in[1],
      (const float*)d_in[2],  (const float*)d_in[3],
      (const float*)d_in[4],  (const float*)d_in[5],
      (const float*)d_in[6],  (const float*)d_in[7],
      (const float*)d_in[8],  (const float*)d_in[9],
      (const float*)d_in[10], (const float*)d_in[11],
      (const float*)d_in[12], (const float*)d_in[13],
      (const float*)d_in[14], (const float*)d_in[15],
      (float*)d_out);
}

// Round 6
// 400.439 us; speedup vs baseline: 1.2683x; 1.0392x over previous
//
#include <hip/hip_runtime.h>

// Fused SFAM, merged-direction kernel: one WG per (b,h) row-pair computes BOTH
// out_l and out_r. Key-side Q projection eliminated:
// S = (Q_l W~_r) x^_r^T + (Q_l b~_r) 1^T, so K = raw-LN x^_r.
// v6: FUSE the two Q matmuls. Q'' = 0.125*(LN(x_l) W~_l^T) W~_r is associative:
// precompute E^T[d][c] = 0.125*lnw_r[d]*lnw_l[c]*sum_o wq_r[o][d]*wq_l[o][c]
// (64x64 bf16, lives in the dead Pt buffer) so Q'' = LN * E^T + f in ONE MFMA
// stage. c = 0.125*Q_l.b~_r collapses to a per-row dot with u[c] =
// lnw_l[c]*sum_o wq_l[o][c]*b~r[o] plus scalar s0 = b~l.b~r.
// Deletes per heavy wave: the whole Q_l stage (16 MFMA + Rs round-trip + 32
// shfl) and BOTH 64-dword uncoalesced weight-gather sets (128 scattered loads
// per lane) -> 8 LDS b128 reads of E. E/u/f/s0 computed by light waves (8-11,
// idle capacity) during projV; +1 barrier.
// Carried from v5: Cauchy-Schwarz softmax shifts (no exact S-stats pass),
// 768 thr = 12 waves, launch_bounds(768,2), 32-col attn groups. 1 WG/CU.

#define HWs  57600      // H*W
#define CHWs 3686400    // C*H*W
#define TOTs 14745600   // B*C*H*W
#define RST  72         // pixel-major row stride (ushort): 64 + 8 pad
#define VST  328        // channel-major row stride (ushort): 320 + 8 pad
#define PTS  36         // Pt row stride (ushort): 32 + 4 pad
#define ETS  72         // E^T row stride (ushort): 64 + 8 pad
#define NTH  768        // 12 waves

typedef short bf16x8 __attribute__((ext_vector_type(8)));
typedef float f32x4  __attribute__((ext_vector_type(4)));
union FragU { uint4 q; unsigned short u[8]; bf16x8 v; };

__device__ __forceinline__ unsigned short f2bf(float f) {
  unsigned u = __float_as_uint(f);
  u += 0x7fffu + ((u >> 16) & 1u);     // RNE
  return (unsigned short)(u >> 16);
}
__device__ __forceinline__ float bf2f(unsigned short s) {
  return __uint_as_float(((unsigned)s) << 16);
}
// monotone float<->uint keys so max-reductions can use native ds_max_u32
__device__ __forceinline__ unsigned fenc(float f) {
  unsigned u = __float_as_uint(f);
  return u ^ (0x80000000u | (unsigned)(-(int)(u >> 31)));
}
__device__ __forceinline__ float fdec(unsigned k) {
  return __uint_as_float(k ^ (0x80000000u | (unsigned)(-(int)((k >> 31) ^ 1u))));
}

__global__ __launch_bounds__(NTH, 2)
void sfam_kernel(
    const float* __restrict__ x_l, const float* __restrict__ x_r,
    const float* __restrict__ ln_l_w, const float* __restrict__ ln_l_b,
    const float* __restrict__ ln_r_w, const float* __restrict__ ln_r_b,
    const float* __restrict__ wq_l, const float* __restrict__ bq_l,
    const float* __restrict__ wq_r, const float* __restrict__ bq_r,
    const float* __restrict__ wv_l, const float* __restrict__ bv_l,
    const float* __restrict__ wv_r, const float* __restrict__ bv_r,
    const float* __restrict__ beta, const float* __restrict__ gamma,
    float* __restrict__ out)
{
  // LDS: 46080+46080+41984+13824 +1280(NX) +2560+2560 +1280(c) +512(BB)
  //      +12(SCu) +256(u)+256(f)+4(s0) ~= 156,688 B  (<= 163840)
  __shared__ __align__(16) unsigned short Rs[320*RST]; // x_l raw -> Q_l'' -> O_r
  __shared__ __align__(16) unsigned short Ks[320*RST]; // x_r raw -> x^_r -> O_l
  __shared__ __align__(16) unsigned short Vb[64*VST];  // V_l then V_r (channel-major)
  __shared__ __align__(16) unsigned short Pt[12*16*PTS];// E^T first, then P->A round-trip
  __shared__ float NX[320];     // ||x^_r_j|| per side-r row
  __shared__ float MU[640], RSd[640];  // LN stats, [0..320)=l, [320..640)=r
  __shared__ float c_arr[320];  // c_wl = 0.125 * Q_l . b~_r
  __shared__ float BB[128];     // [0..64)=b~_l, [64..128)=b~_r
  __shared__ unsigned SCu[3];   // monotone-key maxes: [0]=NXmax [1]=Qn^2max [2]=Cmax
  __shared__ float uArr[64], fArr[64], sS0[1];

  unsigned short* Et = Pt;      // E^T overlay: used before Pt's first attn use

  const int bh = blockIdx.x;
  const int b = bh / 180, h = bh - b*180;
  const int base = b*CHWs + h*320;

  const int t = threadIdx.x;
  const int wave = t >> 6, lane = t & 63;
  const int p = lane & 15, g = lane >> 4;
  // 20 row-tiles over 12 waves: waves 0-7 take 2, waves 8-11 take 1
  const int nwt = (wave < 8) ? 2 : 1;
  const int w0 = (wave < 8) ? wave*32 : 256 + (wave-8)*16;

  if (t < 3) SCu[t] = 0u;   // key 0 is below every real float key

  // ---------- A: staging + inline LN stats (one thread per (side,w)) ----------
  for (int w2 = t; w2 < 640; w2 += NTH) {
    const int side = (w2 >= 320);
    const int w = w2 - side*320;
    const float* xp = side ? x_r : x_l;
    unsigned short* dst = side ? Ks : Rs;
    float s0 = 0.f, q0 = 0.f, s1 = 0.f, q1 = 0.f;
    #pragma unroll
    for (int cb = 0; cb < 64; cb += 8) {
      FragU f;
      #pragma unroll
      for (int j = 0; j < 8; ++j) {
        const float v = xp[base + (cb+j)*HWs + w];
        if (cb < 32) { s0 += v; q0 += v*v; } else { s1 += v; q1 += v*v; }
        f.u[j] = f2bf(v);
      }
      *(uint4*)&dst[w*RST + cb] = f.q;
    }
    const float m  = (s0 + s1) * (1.f/64.f);
    const float vv = (q0 + q1) * (1.f/64.f) - m*m;
    MU[side*320 + w]  = m;
    RSd[side*320 + w] = rsqrtf(vv + 1e-6f);
    if (side) {   // ||x^_r|| = 8*sqrt(v/(v+eps)) -- free from LN stats
      const float vc = fmaxf(vv, 0.f);
      const float nx = 8.f * sqrtf(vc / (vc + 1e-6f));
      NX[w] = nx;
      atomicMax(&SCu[0], fenc(nx));
    }
  }
  if (t < 128) {   // effective Q biases: b~ = bq + (W .* lnw) @ lnb
    const int o = t & 63;
    const float* wqp = (t < 64) ? wq_l : wq_r;
    const float* lwp = (t < 64) ? ln_l_w : ln_r_w;
    const float* lbp = (t < 64) ? ln_l_b : ln_r_b;
    const float* bqp = (t < 64) ? bq_l : bq_r;
    float s = bqp[o];
    for (int c = 0; c < 64; ++c) s += wqp[o*64+c]*lwp[c]*lbp[c];
    BB[t] = s;
  }
  __syncthreads();   // barrier 1: staging, stats, BB visible

  // ---------- V projection (streamed per output tile; all row-local) ----------
  auto projV = [&](const float* wvp, const float* bvp, const unsigned short* src,
                   const float* mup, const float* rsp, bool inv) {
    bf16x8 bx[2][2];
    #pragma unroll
    for (int nt = 0; nt < 2; ++nt) if (nt < nwt) {
      const int w = w0 + nt*16 + p;
      const float mu = mup[w];
      const float sd = inv ? (1.0f / rsp[w]) : 0.f;
      #pragma unroll
      for (int kf = 0; kf < 2; ++kf) {
        FragU f; f.q = *(const uint4*)&src[w*RST + kf*32 + g*8];
        if (inv) {           // recover raw x from normalized: x = x^*sd + mu
          FragU rr;
          #pragma unroll
          for (int j = 0; j < 8; ++j) rr.u[j] = f2bf(bf2f(f.u[j])*sd + mu);
          bx[nt][kf] = rr.v;
        } else bx[nt][kf] = f.v;
      }
    }
    #pragma unroll
    for (int mt = 0; mt < 4; ++mt) {
      bf16x8 av2[2];
      #pragma unroll
      for (int kf = 0; kf < 2; ++kf) {
        FragU rr;
        #pragma unroll
        for (int j = 0; j < 8; ++j) rr.u[j] = f2bf(wvp[(mt*16+p)*64 + kf*32 + g*8 + j]);
        av2[kf] = rr.v;
      }
      f32x4 acc2[2];
      #pragma unroll
      for (int nt = 0; nt < 2; ++nt) acc2[nt] = (f32x4){0.f,0.f,0.f,0.f};
      #pragma unroll
      for (int nt = 0; nt < 2; ++nt) if (nt < nwt)
        #pragma unroll
        for (int kf = 0; kf < 2; ++kf)
          acc2[nt] = __builtin_amdgcn_mfma_f32_16x16x32_bf16(av2[kf], bx[nt][kf], acc2[nt], 0,0,0);
      #pragma unroll
      for (int nt = 0; nt < 2; ++nt) if (nt < nwt)
        #pragma unroll
        for (int r = 0; r < 4; ++r) {
          const int o = mt*16 + g*4 + r;
          Vb[o*VST + w0 + nt*16 + p] = f2bf(acc2[nt][r] + bvp[o]);
        }
    }
  };

  projV(wv_l, bv_l, Rs, MU, RSd, false);   // Vb = V_l (from raw x_l)

  // ---------- light waves: E^T tile + u/f/s0 (heavy waves skip) ----------
  if (wave >= 8) {
    const int dt = wave - 8;
    const float ascale = ln_r_w[dt*16 + p] * 0.125f;
    bf16x8 ar[2];
    #pragma unroll
    for (int kf = 0; kf < 2; ++kf) {
      FragU rr;
      #pragma unroll
      for (int j = 0; j < 8; ++j)
        rr.u[j] = f2bf(wq_r[(kf*32 + g*8 + j)*64 + dt*16 + p] * ascale);
      ar[kf] = rr.v;
    }
    #pragma unroll
    for (int ct = 0; ct < 4; ++ct) {
      const float bscale = ln_l_w[ct*16 + p];
      bf16x8 bl[2];
      #pragma unroll
      for (int kf = 0; kf < 2; ++kf) {
        FragU rr;
        #pragma unroll
        for (int j = 0; j < 8; ++j)
          rr.u[j] = f2bf(wq_l[(kf*32 + g*8 + j)*64 + ct*16 + p] * bscale);
        bl[kf] = rr.v;
      }
      f32x4 ea = (f32x4){0.f,0.f,0.f,0.f};
      ea = __builtin_amdgcn_mfma_f32_16x16x32_bf16(ar[0], bl[0], ea, 0,0,0);
      ea = __builtin_amdgcn_mfma_f32_16x16x32_bf16(ar[1], bl[1], ea, 0,0,0);
      #pragma unroll
      for (int r = 0; r < 4; ++r)
        Et[(dt*16 + g*4 + r)*ETS + ct*16 + p] = f2bf(ea[r]);
    }
  }
  if (t >= 512 && t < 576) {        // u[c] = lnw_l[c] * sum_o wq_l[o][c]*b~r[o]
    const int c = t - 512;
    float s = 0.f;
    for (int o = 0; o < 64; ++o) s += wq_l[o*64 + c] * BB[64 + o];
    uArr[c] = s * ln_l_w[c];
  } else if (t >= 576 && t < 640) { // f[d] = 0.125*lnw_r[d]*sum_o b~l[o]*wq_r[o][d]
    const int d = t - 576;
    float s = 0.f;
    for (int o = 0; o < 64; ++o) s += wq_r[o*64 + d] * BB[o];
    fArr[d] = s * ln_r_w[d] * 0.125f;
  }
  if (t == 640) {                   // s0 = b~l . b~r
    float s = 0.f;
    for (int o = 0; o < 64; ++o) s += BB[o] * BB[64 + o];
    sS0[0] = s;
  }
  __syncthreads();   // barrier 2: Et, uArr, fArr, sS0 visible

  // ---------- fused Q'' = LN(x_l) E^T + f (in place to Rs) + c + row norms ----------
  float rm[2][4];   // dir0 softmax shift: ||Q''_row|| * NXmax
  {
    bf16x8 qa[2][2];
    #pragma unroll
    for (int wt = 0; wt < 2; ++wt) if (wt < nwt) {
      const int w = w0 + wt*16 + p;
      const float mu = MU[w], rs = RSd[w];
      #pragma unroll
      for (int kf = 0; kf < 2; ++kf) {
        FragU f; f.q = *(const uint4*)&Rs[w*RST + kf*32 + g*8];
        FragU rr;
        #pragma unroll
        for (int j = 0; j < 8; ++j) rr.u[j] = f2bf((bf2f(f.u[j]) - mu) * rs);
        qa[wt][kf] = rr.v;
      }
    }
    // c per row (A-layout: lane p owns row w0+wt*16+p, partial over g)
    const float s0v = sS0[0];
    #pragma unroll
    for (int wt = 0; wt < 2; ++wt) if (wt < nwt) {
      float dotp = 0.f;
      #pragma unroll
      for (int kf = 0; kf < 2; ++kf) {
        FragU f; f.v = qa[wt][kf];
        #pragma unroll
        for (int j = 0; j < 8; ++j)
          dotp += bf2f(f.u[j]) * uArr[kf*32 + g*8 + j];
      }
      dotp += __shfl_xor(dotp, 16);
      dotp += __shfl_xor(dotp, 32);
      const float cv = 0.125f * (dotp + s0v);
      if (g == 0) {
        c_arr[w0 + wt*16 + p] = cv;
        atomicMax(&SCu[2], fenc(cv));
      }
    }
    // Q'' MFMA: B-frags from Et (LDS), no global weight gathers
    f32x4 q2[2][4];
    #pragma unroll
    for (int wt = 0; wt < 2; ++wt)
      #pragma unroll
      for (int ct = 0; ct < 4; ++ct) q2[wt][ct] = (f32x4){0.f,0.f,0.f,0.f};
    #pragma unroll
    for (int ct = 0; ct < 4; ++ct) {
      bf16x8 be[2];
      #pragma unroll
      for (int kf = 0; kf < 2; ++kf) {
        FragU f; f.q = *(const uint4*)&Et[(ct*16 + p)*ETS + kf*32 + g*8];
        be[kf] = f.v;
      }
      #pragma unroll
      for (int wt = 0; wt < 2; ++wt) if (wt < nwt)
        #pragma unroll
        for (int kf = 0; kf < 2; ++kf)
          q2[wt][ct] = __builtin_amdgcn_mfma_f32_16x16x32_bf16(qa[wt][kf], be[kf], q2[wt][ct], 0,0,0);
    }
    const float NXmax = fdec(SCu[0]);   // final since staging barrier
    #pragma unroll
    for (int wt = 0; wt < 2; ++wt) {
      #pragma unroll
      for (int r = 0; r < 4; ++r) rm[wt][r] = 0.f;
      if (wt < nwt) {
        #pragma unroll
        for (int r = 0; r < 4; ++r) {
          float qsq = 0.f;
          #pragma unroll
          for (int ct = 0; ct < 4; ++ct) {
            const float qv = q2[wt][ct][r] + fArr[ct*16 + p];
            Rs[(w0 + wt*16 + g*4 + r)*RST + ct*16 + p] = f2bf(qv);
            qsq += qv*qv;
          }
          qsq += __shfl_xor(qsq, 1); qsq += __shfl_xor(qsq, 2);
          qsq += __shfl_xor(qsq, 4); qsq += __shfl_xor(qsq, 8);
          rm[wt][r] = sqrtf(qsq) * NXmax;
          if (p == 0) atomicMax(&SCu[1], fenc(qsq));
        }
      }
    }
  }

  // ---------- normalize Ks in place: x^_r = (x_r - mu) * rs ----------
  #pragma unroll
  for (int wt = 0; wt < 2; ++wt) if (wt < nwt) {
    const int w = w0 + wt*16 + p;
    const float mu = MU[320+w], rs = RSd[320+w];
    #pragma unroll
    for (int kf = 0; kf < 2; ++kf) {
      FragU f; f.q = *(const uint4*)&Ks[w*RST + kf*32 + g*8];
      FragU rr;
      #pragma unroll
      for (int j = 0; j < 8; ++j) rr.u[j] = f2bf((bf2f(f.u[j]) - mu) * rs);
      *(uint4*)&Ks[w*RST + kf*32 + g*8] = rr.q;
    }
  }
  __syncthreads();   // barrier 3: Rs=Q_l'', Ks=x^_r, Vb=V_l, c_arr, SCu visible

  // ---------- persistent A-frags: Q_l'' (for 2a) ----------
  bf16x8 aq[2][2];
  #pragma unroll
  for (int wt = 0; wt < 2; ++wt) if (wt < nwt)
    #pragma unroll
    for (int kf = 0; kf < 2; ++kf) {
      FragU f1; f1.q = *(const uint4*)&Rs[(w0 + wt*16 + p)*RST + kf*32 + g*8];
      aq[wt][kf] = f1.v;
    }

  // ---------- shared attention pass (exp + row-sum + PV), 32-col groups ----------
  float ls[2][4];
  f32x4 oacc[2][4];
  auto attn_pass = [&](bf16x8 (&A)[2][2], const unsigned short* Bsrc,
                       float (&mx)[2][4], bool colc) {
    float rsa[2][4];   // per-lane rowsum partials; one lane-reduce at the end
    #pragma unroll
    for (int wt = 0; wt < 2; ++wt)
      #pragma unroll
      for (int r = 0; r < 4; ++r) rsa[wt][r] = 0.f;
    unsigned short* ptw = &Pt[wave*16*PTS];
    for (int ch = 0; ch < 5; ++ch) {
      const int k0 = ch*64;
      #pragma unroll
      for (int pvk = 0; pvk < 2; ++pvk) {   // 32 score-cols at a time
        bf16x8 bq2[2][2];
        #pragma unroll
        for (int vh = 0; vh < 2; ++vh)
          #pragma unroll
          for (int kf = 0; kf < 2; ++kf) {
            FragU f; f.q = *(const uint4*)&Bsrc[(k0 + (pvk*2+vh)*16 + p)*RST + kf*32 + g*8];
            bq2[vh][kf] = f.v;
          }
        float cc2[2];
        #pragma unroll
        for (int vh = 0; vh < 2; ++vh)
          cc2[vh] = colc ? c_arr[k0 + (pvk*2+vh)*16 + p] : 0.f;
        f32x4 sa[2][2];
        #pragma unroll
        for (int wt = 0; wt < 2; ++wt)
          #pragma unroll
          for (int vh = 0; vh < 2; ++vh) sa[wt][vh] = (f32x4){0.f,0.f,0.f,0.f};
        #pragma unroll
        for (int wt = 0; wt < 2; ++wt) if (wt < nwt)
          #pragma unroll
          for (int vh = 0; vh < 2; ++vh)
            #pragma unroll
            for (int kf = 0; kf < 2; ++kf)
              sa[wt][vh] = __builtin_amdgcn_mfma_f32_16x16x32_bf16(A[wt][kf], bq2[vh][kf], sa[wt][vh], 0,0,0);
        #pragma unroll
        for (int wt = 0; wt < 2; ++wt) if (wt < nwt) {
          #pragma unroll
          for (int r = 0; r < 4; ++r) {
            #pragma unroll
            for (int vh = 0; vh < 2; ++vh) {
              const float e = __expf(sa[wt][vh][r] + cc2[vh] - mx[wt][r]);
              sa[wt][vh][r] = e;
              rsa[wt][r] += e;
            }
          }
        }
        bf16x8 bvv[4];
        #pragma unroll
        for (int ot = 0; ot < 4; ++ot) {
          FragU f; f.q = *(const uint4*)&Vb[(ot*16+p)*VST + k0 + pvk*32 + g*8];
          bvv[ot] = f.v;
        }
        #pragma unroll
        for (int wt = 0; wt < 2; ++wt) if (wt < nwt) {
          #pragma unroll
          for (int vh = 0; vh < 2; ++vh)
            #pragma unroll
            for (int r = 0; r < 4; ++r)
              ptw[(g*4 + r)*PTS + vh*16 + p] = f2bf(sa[wt][vh][r]);
          FragU fa; fa.q = *(const uint4*)&ptw[p*PTS + g*8];
          #pragma unroll
          for (int ot = 0; ot < 4; ++ot)
            oacc[wt][ot] = __builtin_amdgcn_mfma_f32_16x16x32_bf16(fa.v, bvv[ot], oacc[wt][ot], 0,0,0);
        }
      }
    }
    #pragma unroll
    for (int wt = 0; wt < 2; ++wt)
      #pragma unroll
      for (int r = 0; r < 4; ++r) {
        float s = rsa[wt][r];
        s += __shfl_xor(s, 1); s += __shfl_xor(s, 2);
        s += __shfl_xor(s, 4); s += __shfl_xor(s, 8);
        ls[wt][r] = s;
      }
  };

  // ---------- pass 2b: dir1 (l->r). rows = wr, A = x^_r, B = Q_l'', V = V_l ----------
  bf16x8 ak[2][2];   // loaded here, not held earlier
  #pragma unroll
  for (int wt = 0; wt < 2; ++wt) if (wt < nwt)
    #pragma unroll
    for (int kf = 0; kf < 2; ++kf) {
      FragU f2; f2.q = *(const uint4*)&Ks[(w0 + wt*16 + p)*RST + kf*32 + g*8];
      ak[wt][kf] = f2.v;
    }
  float cmR[2][4];   // dir1 shift: nx_wr * Qnmax + Cmax
  {
    const float Qnmax = sqrtf(fdec(SCu[1]));
    const float Cmax  = fdec(SCu[2]);
    #pragma unroll
    for (int wt = 0; wt < 2; ++wt)
      #pragma unroll
      for (int r = 0; r < 4; ++r)
        cmR[wt][r] = (wt < nwt) ? NX[w0 + wt*16 + g*4 + r] * Qnmax + Cmax : 0.f;
  }
  #pragma unroll
  for (int wt = 0; wt < 2; ++wt)
    #pragma unroll
    for (int ot = 0; ot < 4; ++ot) oacc[wt][ot] = (f32x4){0.f,0.f,0.f,0.f};
  attn_pass(ak, Rs, cmR, true);
  __syncthreads();   // everyone done reading Rs (Q_l'') and Vb (V_l)

  // stash O_r -> Rs (normalized by colsum)
  #pragma unroll
  for (int wt = 0; wt < 2; ++wt) if (wt < nwt)
    #pragma unroll
    for (int r = 0; r < 4; ++r) {
      const float inv = 1.0f / ls[wt][r];
      #pragma unroll
      for (int ot = 0; ot < 4; ++ot)
        Rs[(w0 + wt*16 + g*4 + r)*RST + ot*16 + p] = f2bf(oacc[wt][ot][r] * inv);
    }

  // recompute V_r from normalized Ks (inverse LN), overwrite Vb
  projV(wv_r, bv_r, Ks, MU+320, RSd+320, true);
  __syncthreads();

  // ---------- pass 2a: dir0 (r->l). rows = wl, A = Q_l'', B = x^_r, V = V_r ----------
  #pragma unroll
  for (int wt = 0; wt < 2; ++wt)
    #pragma unroll
    for (int ot = 0; ot < 4; ++ot) oacc[wt][ot] = (f32x4){0.f,0.f,0.f,0.f};
  attn_pass(aq, Ks, rm, false);
  __syncthreads();   // everyone done reading Ks (x^_r) and Vb (V_r)

  // stash O_l -> Ks (normalized by rowsum)
  #pragma unroll
  for (int wt = 0; wt < 2; ++wt) if (wt < nwt)
    #pragma unroll
    for (int r = 0; r < 4; ++r) {
      const float inv = 1.0f / ls[wt][r];
      #pragma unroll
      for (int ot = 0; ot < 4; ++ot)
        Ks[(w0 + wt*16 + g*4 + r)*RST + ot*16 + p] = f2bf(oacc[wt][ot][r] * inv);
    }
  __syncthreads();

  // ---------- epilogue: residual add + store, both sides (b128 row reads) ----------
  for (int w2 = t; w2 < 640; w2 += NTH) {
    const int side = (w2 >= 320);
    const int w = w2 - side*320;
    const float* xs = side ? x_r : x_l;
    const unsigned short* Osrc = side ? Rs : Ks;   // O_r in Rs, O_l in Ks
    const float* sc = side ? gamma : beta;
    float* op = out + (side ? TOTs : 0);
    #pragma unroll
    for (int cb = 0; cb < 64; cb += 8) {
      FragU f; f.q = *(const uint4*)&Osrc[w*RST + cb];
      #pragma unroll
      for (int j = 0; j < 8; ++j) {
        const int cc = cb + j;
        const int gi = base + cc*HWs + w;
        op[gi] = xs[gi] + sc[cc] * bf2f(f.u[j]);
      }
    }
  }
}

extern "C" void kernel_launch(void* const* d_in, const int* in_sizes, int n_in,
                              void* d_out, int out_size, void* d_ws, size_t ws_size,
                              hipStream_t stream) {
  (void)in_sizes; (void)n_in; (void)d_ws; (void)ws_size; (void)out_size;
  sfam_kernel<<<dim3(720), dim3(NTH), 0, stream>>>(
      (const float*)d_in[0],  (const float*)d_in[1],
      (const float*)d_in[2],  (const float*)d_in[3],
      (const float*)d_in[4],  (const float*)d_in[5],
      (const float*)d_in[6],  (const float*)d_in[7],
      (const float*)d_in[8],  (const float*)d_in[9],
      (const float*)d_in[10], (const float*)d_in[11],
      (const float*)d_in[12], (const float*)d_in[13],
      (const float*)d_in[14], (const float*)d_in[15],
      (float*)d_out);
}